// Round 4
// baseline (330.331 us; speedup 1.0000x reference)
//
#include <hip/hip_runtime.h>

typedef __bf16 bf16x8 __attribute__((ext_vector_type(8)));
typedef __bf16 bf16x4 __attribute__((ext_vector_type(4)));
typedef float floatx4 __attribute__((ext_vector_type(4)));

// Sizes (fixed): B=4, P=2048, DIM=1024, H=16, HKV=8, D=64
#define BSZ 4
#define SEQ 2048
#define DIM 1024
#define NH 16
#define NKV 8
#define HD 64

// async global->LDS, 16B per lane; LDS dest = wave-uniform base + lane*16
#define GLDS16(g, l) __builtin_amdgcn_global_load_lds(                        \
    (const __attribute__((address_space(1))) void*)(g),                       \
    (__attribute__((address_space(3))) void*)(l), 16, 0, 0)

// ---------------------------------------------------------------------------
// Kernel 0: merged prep.
//   blocks [0,2048): x (f32) -> xb (bf16); block 0 zeroes partial[0..31]
//   blocks [2048,2816): W transpose to bf16 [N][K]
//     Wt rows 0..1023 = Wq^T, 1024..1535 = Wk^T, 1536..2047 = Wv^T; Wpt = Wp^T
// ---------------------------------------------------------------------------
__global__ __launch_bounds__(256) void prep_kernel(
    const float* __restrict__ x,
    const float* __restrict__ Wq, const float* __restrict__ Wk,
    const float* __restrict__ Wv, const float* __restrict__ Wp,
    __bf16* __restrict__ xb, __bf16* __restrict__ Wt, __bf16* __restrict__ Wpt,
    float* __restrict__ partial)
{
    __shared__ __bf16 T[64][72];   // [c][k], pad 72
    const int bid = blockIdx.x;
    const int tid = threadIdx.x;

    if (bid < 2048) {
        if (bid == 0 && tid < 32) partial[tid] = 0.f;
        size_t i = ((size_t)bid * 256 + tid) * 16;
#pragma unroll
        for (int q = 0; q < 2; ++q) {
            float4 a = *(const float4*)&x[i + q * 8];
            float4 b = *(const float4*)&x[i + q * 8 + 4];
            bf16x8 o;
            o[0] = (__bf16)a.x; o[1] = (__bf16)a.y; o[2] = (__bf16)a.z; o[3] = (__bf16)a.w;
            o[4] = (__bf16)b.x; o[5] = (__bf16)b.y; o[6] = (__bf16)b.z; o[7] = (__bf16)b.w;
            *(bf16x8*)&xb[i + q * 8] = o;
        }
        return;
    }

    const int t  = bid - 2048;
    const int k0 = (t & 15) * 64;
    const int cg = (t >> 4) * 64;

    const float* W; int ldn, cl, orow; __bf16* out;
    if (cg < 1024)      { W = Wq; ldn = 1024; cl = cg;        out = Wt;  orow = cg; }
    else if (cg < 1536) { W = Wk; ldn = 512;  cl = cg - 1024; out = Wt;  orow = cg; }
    else if (cg < 2048) { W = Wv; ldn = 512;  cl = cg - 1536; out = Wt;  orow = cg; }
    else                { W = Wp; ldn = 1024; cl = cg - 2048; out = Wpt; orow = cg - 2048; }

    const int kr = tid >> 2;            // tile row (k), 0..63
    const int cq = (tid & 3) * 16;      // tile col base (c)
#pragma unroll
    for (int j = 0; j < 4; ++j) {
        float4 f = *(const float4*)&W[(size_t)(k0 + kr) * ldn + cl + cq + j * 4];
        T[cq + j * 4 + 0][kr] = (__bf16)f.x;
        T[cq + j * 4 + 1][kr] = (__bf16)f.y;
        T[cq + j * 4 + 2][kr] = (__bf16)f.z;
        T[cq + j * 4 + 3][kr] = (__bf16)f.w;
    }
    __syncthreads();
#pragma unroll
    for (int j = 0; j < 2; ++j) {
        int ch = tid * 2 + j;                 // 512 chunks of 16B
        int c = ch >> 3, kc = (ch & 7) * 8;
        *(bf16x8*)&out[(size_t)(orow + c) * 1024 + k0 + kc] = *(bf16x8*)&T[c][kc];
    }
}

// ---------------------------------------------------------------------------
// GEMM v2 structure (both qkv and proj): 256x128 tile, BK=64, 512 threads
// (8 waves, wave tile 64x64, acc[4][4] as before).  Double-buffered LDS;
// next tile's global_load_lds issued BEFORE current tile's compute; ONE
// barrier per K-step (compiler emits vmcnt(0)+lgkmcnt(0) before s_barrier).
// LDS rows are 128B -> 16B-chunk XOR swizzle (chunk ^= row&7) applied via
// pre-swizzled GLOBAL source (m173 pattern: GLDS dest stays linear) and the
// matching XOR on the ds_read side.  Bank-exact: conflict-free reads.
// ---------------------------------------------------------------------------
#define STAGE(bufi, kof)                                                      \
    {                                                                         \
        _Pragma("unroll") for (int i = 0; i < 4; ++i)                         \
            GLDS16(Ag + (kof) + i * 64 * 1024, &As[bufi][i * 4096 + w512]);   \
        _Pragma("unroll") for (int i = 0; i < 2; ++i)                         \
            GLDS16(Bg + (kof) + i * 64 * 1024, &Bs[bufi][i * 4096 + w512]);   \
    }

// ---------------------------------------------------------------------------
// Kernel 1: fused QKV projection + k sum-of-squares.
// xb(bf16) @ Wt(bf16,[c][k]) -> q,k (bf16 [B][H][P][D]), v^T ([B][HKV][D][P]).
// grid (16, 32): c-blocks 128 wide, m-blocks 256 tall.
// ---------------------------------------------------------------------------
__global__ __launch_bounds__(512) void qkv_gemm(
    const __bf16* __restrict__ xb, const __bf16* __restrict__ Wt,
    __bf16* __restrict__ qw, __bf16* __restrict__ kw, __bf16* __restrict__ vw,
    float* __restrict__ partial)
{
    __shared__ __align__(16) __bf16 As[2][256 * 64];   // 32 KB per buf
    __shared__ __align__(16) __bf16 Bs[2][128 * 64];   // 16 KB per buf

    const int m0 = blockIdx.y * 256;
    const int c0 = blockIdx.x * 128;

    const int tid  = threadIdx.x;
    const int lane = tid & 63, wv = tid >> 6;
    const int l16  = lane & 15, quad = lane >> 4;
    const int wr = (wv >> 1) * 64, wc = (wv & 1) * 64;   // 4 row x 2 col waves
    const int w512 = wv * 512;

    // staging: lane covers (row = wv*8 + lane/8, chunk = lane%8), rounds +64 rows
    const int srow = wv * 8 + (lane >> 3);
    const int scol = ((lane & 7) ^ (lane >> 3)) * 8;     // pre-swizzled source
    const __bf16* Ag = xb + (size_t)(m0 + srow) * 1024 + scol;
    const __bf16* Bg = Wt + (size_t)(c0 + srow) * 1024 + scol;

    // ds_read chunk offsets (elements) for k-halves h=0,1
    const int sw0 = ((quad)     ^ (l16 & 7)) * 8;
    const int sw1 = ((4 + quad) ^ (l16 & 7)) * 8;

    floatx4 acc[4][4] = {};

    STAGE(0, 0);
    __syncthreads();

    for (int t = 0; t < 16; ++t) {
        const int cur = t & 1;
        if (t < 15) STAGE(cur ^ 1, (t + 1) * 64);

        bf16x8 af[4][2], bfr[4][2];
#pragma unroll
        for (int tt = 0; tt < 4; ++tt) {
            const int ar = (wr + tt * 16 + l16) * 64;
            af[tt][0] = *(bf16x8*)&As[cur][ar + sw0];
            af[tt][1] = *(bf16x8*)&As[cur][ar + sw1];
            const int br = (wc + tt * 16 + l16) * 64;
            bfr[tt][0] = *(bf16x8*)&Bs[cur][br + sw0];
            bfr[tt][1] = *(bf16x8*)&Bs[cur][br + sw1];
        }
#pragma unroll
        for (int mt = 0; mt < 4; ++mt)
#pragma unroll
            for (int nt = 0; nt < 4; ++nt) {
                acc[mt][nt] = __builtin_amdgcn_mfma_f32_16x16x32_bf16(
                    af[mt][0], bfr[nt][0], acc[mt][nt], 0, 0, 0);
                acc[mt][nt] = __builtin_amdgcn_mfma_f32_16x16x32_bf16(
                    af[mt][1], bfr[nt][1], acc[mt][nt], 0, 0, 0);
            }
        __syncthreads();
    }

    float ss = 0.f;
#pragma unroll
    for (int mt = 0; mt < 4; ++mt) {
#pragma unroll
        for (int nt = 0; nt < 4; ++nt) {
#pragma unroll
            for (int r = 0; r < 4; ++r) {
                int m = m0 + wr + mt * 16 + quad * 4 + r;
                int c = c0 + wc + nt * 16 + l16;
                int bb = m >> 11, p = m & 2047;
                float val = acc[mt][nt][r];
                if (c < 1024) {
                    int h = c >> 6, d = c & 63;
                    qw[(((size_t)bb * NH + h) * SEQ + p) * HD + d] = (__bf16)(val * 0.125f);
                } else if (c < 1536) {
                    int cc = c - 1024, hh = cc >> 6, d = cc & 63;
                    kw[(((size_t)bb * NKV + hh) * SEQ + p) * HD + d] = (__bf16)val;
                    ss += val * val;
                } else {
                    int cc = c - 1536, hh = cc >> 6, d = cc & 63;
                    vw[(((size_t)bb * NKV + hh) * HD + d) * SEQ + p] = (__bf16)val;
                }
            }
        }
    }

    if (c0 >= 1024 && c0 < 1536) {   // k-region: wave reduce + one atomic/wave
#pragma unroll
        for (int off = 1; off < 64; off <<= 1) ss += __shfl_xor(ss, off, 64);
        if (lane == 0) {
            int bb = m0 >> 11;
            int hh = (c0 - 1024 + wc) >> 6;   // wave-uniform: 0..7
            atomicAdd(&partial[bb * 8 + hh], ss);
        }
    }
}

// ---------------------------------------------------------------------------
// Kernel 3: ratios + kv_id.  partial[b*8+j] = sum of squares of k for (b,j).
// ---------------------------------------------------------------------------
__global__ void ratios_kernel(const float* __restrict__ partial,
                              const float* __restrict__ cache,
                              int* __restrict__ kv_id)
{
    if (threadIdx.x != 0 || blockIdx.x != 0) return;
    float mag[8] = {0.f, 0.f, 0.f, 0.f, 0.f, 0.f, 0.f, 0.f};
    for (int b = 0; b < 4; ++b)
        for (int j = 0; j < 8; ++j) mag[j] += sqrtf(partial[b * 8 + j]);
    float diff[8], sum = 0.f;
    for (int j = 0; j < 8; ++j) {
        diff[j] = fabsf(cache[j] - mag[j]);
        sum += diff[j];
    }
    int r[8], s = 0;
    for (int j = 0; j < 8; ++j) {
        r[j] = (int)rintf(diff[j] / sum * 16.0f);  // round half to even (jnp.round)
        s += r[j];
    }
    while (s > 16) {
        int jm = 0;
        for (int j = 1; j < 8; ++j) if (r[j] > r[jm]) jm = j;
        r[jm]--; s--;
    }
    while (s < 16) {
        int jm = 0;
        for (int j = 1; j < 8; ++j) if (r[j] < r[jm]) jm = j;
        r[jm]++; s++;
    }
    int cum[8], c = 0;
    for (int j = 0; j < 8; ++j) { c += r[j]; cum[j] = c; }
    for (int h = 0; h < 16; ++h) {
        int j = 0;
        while (j < 7 && cum[j] <= h) j++;  // searchsorted side='right'
        kv_id[h] = j;
    }
}

// ---------------------------------------------------------------------------
// Kernel 4: flash attention (unchanged structure from round 3, + s_setprio
// around the MFMA clusters).  P in registers, no cross-lane ops; V^T B-operand
// read with the matching key permutation; double-buffered K/V; one barrier.
// ---------------------------------------------------------------------------
__global__ __launch_bounds__(256, 4) void attn_kernel(
    const __bf16* __restrict__ qw, const __bf16* __restrict__ kw,
    const __bf16* __restrict__ vw, const int* __restrict__ kv_id,
    __bf16* __restrict__ attn_out)
{
    __shared__ __align__(16) __bf16 Kt[2][64 * 72];    // [key][d], pad 72
    __shared__ __align__(16) __bf16 VT[2][64 * 72];    // [d][key], pad 72

    const int bh = blockIdx.y;           // 0..63
    const int b = bh >> 4, h = bh & 15;
    const int q0 = blockIdx.x * 128;
    const int kv = kv_id[h];

    const __bf16* Kg = kw + ((size_t)(b * NKV + kv) * SEQ) * HD;    // [p][d]
    const __bf16* Vg = vw + ((size_t)(b * NKV + kv) * HD) * SEQ;    // [d][p]
    const __bf16* Qg = qw + ((size_t)(b * NH + h) * SEQ + q0) * HD;

    const int tid  = threadIdx.x;
    const int lane = tid & 63, wv = tid >> 6;
    const int l16  = lane & 15, quad = lane >> 4;

    // Two independent Q fragment sets: qrow = 32*wv + 16*s + l16
    bf16x8 qf[2][2];
#pragma unroll
    for (int s = 0; s < 2; ++s) {
        const __bf16* qp = &Qg[(size_t)(32 * wv + 16 * s + l16) * HD];
        qf[s][0] = *(const bf16x8*)&qp[quad * 8];
        qf[s][1] = *(const bf16x8*)&qp[32 + quad * 8];
    }

    float l_acc[2] = {0.f, 0.f};
    floatx4 o[2][4] = {};

    // staging geometry: thread covers (row = tid>>2, 32B chunk = (tid&3)*16)
    const int row = tid >> 2, cc = (tid & 3) << 4;
    const __bf16* kp = Kg + (size_t)row * HD + cc;    // +4096/tile
    const __bf16* vp = Vg + (size_t)row * SEQ + cc;   // +64/tile

    // prologue: tile 0 -> buf 0
    bf16x8 rk0 = *(const bf16x8*)kp;
    bf16x8 rk1 = *(const bf16x8*)(kp + 8);
    bf16x8 rv0 = *(const bf16x8*)vp;
    bf16x8 rv1 = *(const bf16x8*)(vp + 8);
    {
        __bf16* kd = &Kt[0][row * 72 + cc];
        *(bf16x8*)kd = rk0; *(bf16x8*)(kd + 8) = rk1;
        __bf16* vd = &VT[0][row * 72 + cc];
        *(bf16x8*)vd = rv0; *(bf16x8*)(vd + 8) = rv1;
    }
    __syncthreads();

    for (int kb = 0; kb < 32; ++kb) {
        const int cur = kb & 1;
        const __bf16* Kc = &Kt[cur][0];
        const __bf16* Vc = &VT[cur][0];

        // ---- QK^T: S^T[key][q], two q-sets share K fragments ---------------
        floatx4 sacc[2][4] = {};
        {
            bf16x8 kf[4];
#pragma unroll
            for (int t = 0; t < 4; ++t)
                kf[t] = *(bf16x8*)&Kc[(16 * t + l16) * 72 + quad * 8];
            __builtin_amdgcn_s_setprio(1);
#pragma unroll
            for (int t = 0; t < 4; ++t) {
                sacc[0][t] = __builtin_amdgcn_mfma_f32_16x16x32_bf16(kf[t], qf[0][0], sacc[0][t], 0, 0, 0);
                sacc[1][t] = __builtin_amdgcn_mfma_f32_16x16x32_bf16(kf[t], qf[1][0], sacc[1][t], 0, 0, 0);
            }
            __builtin_amdgcn_s_setprio(0);
#pragma unroll
            for (int t = 0; t < 4; ++t)
                kf[t] = *(bf16x8*)&Kc[(16 * t + l16) * 72 + 32 + quad * 8];
            __builtin_amdgcn_s_setprio(1);
#pragma unroll
            for (int t = 0; t < 4; ++t) {
                sacc[0][t] = __builtin_amdgcn_mfma_f32_16x16x32_bf16(kf[t], qf[0][1], sacc[0][t], 0, 0, 0);
                sacc[1][t] = __builtin_amdgcn_mfma_f32_16x16x32_bf16(kf[t], qf[1][1], sacc[1][t], 0, 0, 0);
            }
            __builtin_amdgcn_s_setprio(0);
        }

        // ---- prefetch next K/V tile into registers (hides under softmax+PV)
        if (kb < 31) {
            const __bf16* kn = kp + (size_t)(kb + 1) * (64 * HD);
            const __bf16* vn = vp + (kb + 1) * 64;
            rk0 = *(const bf16x8*)kn;
            rk1 = *(const bf16x8*)(kn + 8);
            rv0 = *(const bf16x8*)vn;
            rv1 = *(const bf16x8*)(vn + 8);
        }

        // ---- softmax (fixed shift) -> per-lane packed PV A-operand ---------
        // lane (l16,quad) reg (t,r) holds P[q=l16][key=16t+4*quad+r].
        // A-op element e <- p[e>>2][e&3]; key order kappa(q,e)=16*(e>>2)+4q+(e&3).
        bf16x8 a0s[2], a1s[2];
#pragma unroll
        for (int s = 0; s < 2; ++s) {
            bf16x8 a0, a1;
#pragma unroll
            for (int r = 0; r < 4; ++r) {
                float e0 = __expf(sacc[s][0][r] - 10.f); l_acc[s] += e0;
                float e1 = __expf(sacc[s][1][r] - 10.f); l_acc[s] += e1;
                float e2 = __expf(sacc[s][2][r] - 10.f); l_acc[s] += e2;
                float e3 = __expf(sacc[s][3][r] - 10.f); l_acc[s] += e3;
                a0[r] = (__bf16)e0; a0[4 + r] = (__bf16)e1;
                a1[r] = (__bf16)e2; a1[4 + r] = (__bf16)e3;
            }
            a0s[s] = a0; a1s[s] = a1;
        }

        // ---- O += P V; B-operand read with matching key permutation --------
        __builtin_amdgcn_s_setprio(1);
#pragma unroll
        for (int dt = 0; dt < 4; ++dt) {
            const __bf16* vrow = &Vc[(16 * dt + l16) * 72 + 4 * quad];
            bf16x4 lo0 = *(const bf16x4*)vrow;          // keys  4q..+3
            bf16x4 hi0 = *(const bf16x4*)(vrow + 16);   // keys 16+4q..+3
            bf16x8 vb0 = __builtin_shufflevector(lo0, hi0, 0, 1, 2, 3, 4, 5, 6, 7);
            o[0][dt] = __builtin_amdgcn_mfma_f32_16x16x32_bf16(a0s[0], vb0, o[0][dt], 0, 0, 0);
            o[1][dt] = __builtin_amdgcn_mfma_f32_16x16x32_bf16(a0s[1], vb0, o[1][dt], 0, 0, 0);
            bf16x4 lo1 = *(const bf16x4*)(vrow + 32);   // keys 32+4q..+3
            bf16x4 hi1 = *(const bf16x4*)(vrow + 48);   // keys 48+4q..+3
            bf16x8 vb1 = __builtin_shufflevector(lo1, hi1, 0, 1, 2, 3, 4, 5, 6, 7);
            o[0][dt] = __builtin_amdgcn_mfma_f32_16x16x32_bf16(a1s[0], vb1, o[0][dt], 0, 0, 0);
            o[1][dt] = __builtin_amdgcn_mfma_f32_16x16x32_bf16(a1s[1], vb1, o[1][dt], 0, 0, 0);
        }
        __builtin_amdgcn_s_setprio(0);

        // ---- write prefetched tile to the other buffer, single barrier ----
        if (kb < 31) {
            __bf16* kd = &Kt[cur ^ 1][row * 72 + cc];
            *(bf16x8*)kd = rk0; *(bf16x8*)(kd + 8) = rk1;
            __bf16* vd = &VT[cur ^ 1][row * 72 + cc];
            *(bf16x8*)vd = rv0; *(bf16x8*)(vd + 8) = rv1;
        }
        __syncthreads();
    }

    // epilogue per set: finish denominator, scale, store [B][P][H][D]
#pragma unroll
    for (int s = 0; s < 2; ++s) {
        float l = l_acc[s];
        l += __shfl_xor(l, 16, 64);
        l += __shfl_xor(l, 32, 64);   // lane holds denom for qrow 32wv+16s+l16
#pragma unroll
        for (int r = 0; r < 4; ++r) {
            float lr = __shfl(l, quad * 4 + r, 64);   // denom of row-offset quad*4+r
            float inv = 1.f / lr;
            int p_ = q0 + 32 * wv + 16 * s + quad * 4 + r;
#pragma unroll
            for (int dt = 0; dt < 4; ++dt) {
                int d = 16 * dt + l16;
                attn_out[(((size_t)b * SEQ + p_) * NH + h) * HD + d] = (__bf16)(o[s][dt][r] * inv);
            }
        }
    }
}

// ---------------------------------------------------------------------------
// Kernel 5: output projection, v2 GEMM structure.
// attn[8192][1024](bf16) @ Wpt(bf16,[c][k]) + bp(f32) -> out (f32)
// grid (8, 32).
// ---------------------------------------------------------------------------
__global__ __launch_bounds__(512) void proj_gemm(
    const __bf16* __restrict__ A, const __bf16* __restrict__ Wpt,
    const float* __restrict__ bp, float* __restrict__ out)
{
    __shared__ __align__(16) __bf16 As[2][256 * 64];
    __shared__ __align__(16) __bf16 Bs[2][128 * 64];

    const int m0 = blockIdx.y * 256;
    const int c0 = blockIdx.x * 128;

    const int tid  = threadIdx.x;
    const int lane = tid & 63, wv = tid >> 6;
    const int l16  = lane & 15, quad = lane >> 4;
    const int wr = (wv >> 1) * 64, wc = (wv & 1) * 64;
    const int w512 = wv * 512;

    const int srow = wv * 8 + (lane >> 3);
    const int scol = ((lane & 7) ^ (lane >> 3)) * 8;
    const __bf16* Ag = A   + (size_t)(m0 + srow) * 1024 + scol;
    const __bf16* Bg = Wpt + (size_t)(c0 + srow) * 1024 + scol;

    const int sw0 = ((quad)     ^ (l16 & 7)) * 8;
    const int sw1 = ((4 + quad) ^ (l16 & 7)) * 8;

    floatx4 acc[4][4] = {};

    STAGE(0, 0);
    __syncthreads();

    for (int t = 0; t < 16; ++t) {
        const int cur = t & 1;
        if (t < 15) STAGE(cur ^ 1, (t + 1) * 64);

        bf16x8 af[4][2], bfr[4][2];
#pragma unroll
        for (int tt = 0; tt < 4; ++tt) {
            const int ar = (wr + tt * 16 + l16) * 64;
            af[tt][0] = *(bf16x8*)&As[cur][ar + sw0];
            af[tt][1] = *(bf16x8*)&As[cur][ar + sw1];
            const int br = (wc + tt * 16 + l16) * 64;
            bfr[tt][0] = *(bf16x8*)&Bs[cur][br + sw0];
            bfr[tt][1] = *(bf16x8*)&Bs[cur][br + sw1];
        }
#pragma unroll
        for (int mt = 0; mt < 4; ++mt)
#pragma unroll
            for (int nt = 0; nt < 4; ++nt) {
                acc[mt][nt] = __builtin_amdgcn_mfma_f32_16x16x32_bf16(
                    af[mt][0], bfr[nt][0], acc[mt][nt], 0, 0, 0);
                acc[mt][nt] = __builtin_amdgcn_mfma_f32_16x16x32_bf16(
                    af[mt][1], bfr[nt][1], acc[mt][nt], 0, 0, 0);
            }
        __syncthreads();
    }

#pragma unroll
    for (int nt = 0; nt < 4; ++nt) {
        int c = c0 + wc + nt * 16 + l16;
        float bias = bp[c];
#pragma unroll
        for (int mt = 0; mt < 4; ++mt)
#pragma unroll
            for (int r = 0; r < 4; ++r) {
                int m = m0 + wr + mt * 16 + quad * 4 + r;
                out[(size_t)m * 1024 + c] = acc[mt][nt][r] + bias;
            }
    }
}

// ---------------------------------------------------------------------------
extern "C" void kernel_launch(void* const* d_in, const int* in_sizes, int n_in,
                              void* d_out, int out_size, void* d_ws, size_t ws_size,
                              hipStream_t stream)
{
    const float* x     = (const float*)d_in[0];
    const float* Wq    = (const float*)d_in[1];
    const float* Wk    = (const float*)d_in[2];
    const float* Wv    = (const float*)d_in[3];
    const float* Wp    = (const float*)d_in[4];
    const float* bp    = (const float*)d_in[5];
    const float* cache = (const float*)d_in[6];
    float* outp = (float*)d_out;

    __bf16* ws = (__bf16*)d_ws;
    __bf16* qw  = ws;                                    // [B][H][P][D]      16 MB
    __bf16* kw  = qw + (size_t)BSZ * NH * SEQ * HD;      // [B][HKV][P][D]     8 MB
    __bf16* vw  = kw + (size_t)BSZ * NKV * SEQ * HD;     // [B][HKV][D][P]     8 MB
    __bf16* at  = vw + (size_t)BSZ * NKV * SEQ * HD;     // [B][P][H*D]       16 MB
    __bf16* xb  = at + (size_t)BSZ * NH * SEQ * HD;      // x in bf16         16 MB
    __bf16* Wt  = xb + (size_t)BSZ * SEQ * DIM;          // [Wq|Wk|Wv]^T bf16  4 MB
    __bf16* Wpt = Wt + (size_t)2048 * 1024;              // Wp^T bf16          2 MB
    float* partial = (float*)(Wpt + (size_t)1024 * 1024);  // 32 floats
    int*   kv_id   = (int*)(partial + 32);                 // 16 ints

    prep_kernel<<<2816, 256, 0, stream>>>(x, Wq, Wk, Wv, Wp, xb, Wt, Wpt, partial);
    qkv_gemm<<<dim3(16, 32), 512, 0, stream>>>(xb, Wt, qw, kw, vw, partial);
    ratios_kernel<<<1, 64, 0, stream>>>(partial, cache, kv_id);
    attn_kernel<<<dim3(16, 64), 256, 0, stream>>>(qw, kw, vw, kv_id, at);
    proj_gemm<<<dim3(8, 32), 512, 0, stream>>>(at, Wpt, bp, outp);
}

// Round 5
// 288.696 us; speedup vs baseline: 1.1442x; 1.1442x over previous
//
#include <hip/hip_runtime.h>

typedef __bf16 bf16x8 __attribute__((ext_vector_type(8)));
typedef __bf16 bf16x4 __attribute__((ext_vector_type(4)));
typedef float floatx4 __attribute__((ext_vector_type(4)));

// Sizes (fixed): B=4, P=2048, DIM=1024, H=16, HKV=8, D=64
#define BSZ 4
#define SEQ 2048
#define DIM 1024
#define NH 16
#define NKV 8
#define HD 64

// async global->LDS, 16B per lane; LDS dest = wave-uniform base + lane*16
#define GLDS16(g, l) __builtin_amdgcn_global_load_lds(                        \
    (const __attribute__((address_space(1))) void*)(g),                       \
    (__attribute__((address_space(3))) void*)(l), 16, 0, 0)

// ---------------------------------------------------------------------------
// Kernel 0: merged prep.
//   blocks [0,2048): x (f32) -> xb (bf16)
//   blocks [2048,2816): W transpose to bf16 [N][K]
//     Wt rows 0..1023 = Wq^T, 1024..1535 = Wk^T, 1536..2047 = Wv^T; Wpt = Wp^T
// ---------------------------------------------------------------------------
__global__ __launch_bounds__(256) void prep_kernel(
    const float* __restrict__ x,
    const float* __restrict__ Wq, const float* __restrict__ Wk,
    const float* __restrict__ Wv, const float* __restrict__ Wp,
    __bf16* __restrict__ xb, __bf16* __restrict__ Wt, __bf16* __restrict__ Wpt)
{
    __shared__ __bf16 T[64][72];   // [c][k], pad 72
    const int bid = blockIdx.x;
    const int tid = threadIdx.x;

    if (bid < 2048) {
        size_t i = ((size_t)bid * 256 + tid) * 16;
#pragma unroll
        for (int q = 0; q < 2; ++q) {
            float4 a = *(const float4*)&x[i + q * 8];
            float4 b = *(const float4*)&x[i + q * 8 + 4];
            bf16x8 o;
            o[0] = (__bf16)a.x; o[1] = (__bf16)a.y; o[2] = (__bf16)a.z; o[3] = (__bf16)a.w;
            o[4] = (__bf16)b.x; o[5] = (__bf16)b.y; o[6] = (__bf16)b.z; o[7] = (__bf16)b.w;
            *(bf16x8*)&xb[i + q * 8] = o;
        }
        return;
    }

    const int t  = bid - 2048;
    const int k0 = (t & 15) * 64;
    const int cg = (t >> 4) * 64;

    const float* W; int ldn, cl, orow; __bf16* out;
    if (cg < 1024)      { W = Wq; ldn = 1024; cl = cg;        out = Wt;  orow = cg; }
    else if (cg < 1536) { W = Wk; ldn = 512;  cl = cg - 1024; out = Wt;  orow = cg; }
    else if (cg < 2048) { W = Wv; ldn = 512;  cl = cg - 1536; out = Wt;  orow = cg; }
    else                { W = Wp; ldn = 1024; cl = cg - 2048; out = Wpt; orow = cg - 2048; }

    const int kr = tid >> 2;            // tile row (k), 0..63
    const int cq = (tid & 3) * 16;      // tile col base (c)
#pragma unroll
    for (int j = 0; j < 4; ++j) {
        float4 f = *(const float4*)&W[(size_t)(k0 + kr) * ldn + cl + cq + j * 4];
        T[cq + j * 4 + 0][kr] = (__bf16)f.x;
        T[cq + j * 4 + 1][kr] = (__bf16)f.y;
        T[cq + j * 4 + 2][kr] = (__bf16)f.z;
        T[cq + j * 4 + 3][kr] = (__bf16)f.w;
    }
    __syncthreads();
#pragma unroll
    for (int j = 0; j < 2; ++j) {
        int ch = tid * 2 + j;                 // 512 chunks of 16B
        int c = ch >> 3, kc = (ch & 7) * 8;
        *(bf16x8*)&out[(size_t)(orow + c) * 1024 + k0 + kc] = *(bf16x8*)&T[c][kc];
    }
}

// ---------------------------------------------------------------------------
// Kernel 1: fused QKV projection, m97-style: 128x128 tile, BK=32, linear LDS,
// global_load_lds width-16 staging.  xb(bf16) @ Wt(bf16, [c][k]) ->
// q,k (bf16 [B][H][P][D]) and v TRANSPOSED (bf16 [B][HKV][D][P]). q *= 0.125.
// (round-3 proven version; round-4's 512-thread variant killed the 2-block/CU
//  wave overlap -- m132 failure mode -- and was reverted)
// ---------------------------------------------------------------------------
__global__ __launch_bounds__(256) void qkv_gemm(
    const __bf16* __restrict__ xb, const __bf16* __restrict__ Wt,
    __bf16* __restrict__ qw, __bf16* __restrict__ kw, __bf16* __restrict__ vw)
{
    __shared__ __align__(16) __bf16 As[128 * 32];   // [m][kk] linear
    __shared__ __align__(16) __bf16 Bs[128 * 32];   // [c][kk] linear

    const int m0 = blockIdx.y * 128;
    const int c0 = blockIdx.x * 128;

    const int tid  = threadIdx.x;
    const int lane = tid & 63, wv = tid >> 6;
    const int l16  = lane & 15, quad = lane >> 4;
    const int wr = (wv >> 1) * 64, wc = (wv & 1) * 64;

    const int srow = wv * 16 + (lane >> 2);
    const int skc  = (lane & 3) * 8;
    const __bf16* Ag = xb + (size_t)(m0 + srow) * 1024 + skc;
    const __bf16* Bg = Wt + (size_t)(c0 + srow) * 1024 + skc;
    __bf16* lA = As + wv * 512;   // wave-uniform LDS bases
    __bf16* lB = Bs + wv * 512;

    floatx4 acc[4][4] = {};

    for (int k0 = 0; k0 < 1024; k0 += 32) {
        GLDS16(Ag + k0,             lA);
        GLDS16(Ag + k0 + 64 * 1024, lA + 2048);
        GLDS16(Bg + k0,             lB);
        GLDS16(Bg + k0 + 64 * 1024, lB + 2048);
        __syncthreads();

        bf16x8 af[4], bfr[4];
#pragma unroll
        for (int t = 0; t < 4; ++t) {
            af[t]  = *(bf16x8*)&As[(wr + t * 16 + l16) * 32 + quad * 8];
            bfr[t] = *(bf16x8*)&Bs[(wc + t * 16 + l16) * 32 + quad * 8];
        }
#pragma unroll
        for (int mt = 0; mt < 4; ++mt)
#pragma unroll
            for (int nt = 0; nt < 4; ++nt)
                acc[mt][nt] = __builtin_amdgcn_mfma_f32_16x16x32_bf16(
                    af[mt], bfr[nt], acc[mt][nt], 0, 0, 0);
        __syncthreads();
    }

#pragma unroll
    for (int mt = 0; mt < 4; ++mt) {
#pragma unroll
        for (int nt = 0; nt < 4; ++nt) {
#pragma unroll
            for (int r = 0; r < 4; ++r) {
                int m = m0 + wr + mt * 16 + quad * 4 + r;
                int c = c0 + wc + nt * 16 + l16;
                int bb = m >> 11, p = m & 2047;
                float val = acc[mt][nt][r];
                if (c < 1024) {
                    int h = c >> 6, d = c & 63;
                    qw[(((size_t)bb * NH + h) * SEQ + p) * HD + d] = (__bf16)(val * 0.125f);
                } else if (c < 1536) {
                    int cc = c - 1024, hh = cc >> 6, d = cc & 63;
                    kw[(((size_t)bb * NKV + hh) * SEQ + p) * HD + d] = (__bf16)val;
                } else {
                    int cc = c - 1536, hh = cc >> 6, d = cc & 63;
                    vw[(((size_t)bb * NKV + hh) * HD + d) * SEQ + p] = (__bf16)val;
                }
            }
        }
    }
}

// ---------------------------------------------------------------------------
// Kernel 2: partial sum-of-squares of k. 256 blocks: (b*8+kv)*8 + slice.
// (standalone on purpose: it also absorbs qkv's L2 writeback before attn --
//  round-4 fusion made attn inherit ~74 MB of flush traffic)
// ---------------------------------------------------------------------------
__global__ __launch_bounds__(256) void ksumsq(const __bf16* __restrict__ kw,
                                              float* __restrict__ partial)
{
    const int blk = blockIdx.x;
    const __bf16* base = kw + (size_t)(blk >> 3) * (SEQ * HD)
                            + (size_t)(blk & 7) * (SEQ * HD / 8);
    const int tid = threadIdx.x;

    float s = 0.f;
#pragma unroll
    for (int i = tid * 8; i < SEQ * HD / 8; i += 256 * 8) {
        bf16x8 vv = *(const bf16x8*)&base[i];
#pragma unroll
        for (int j = 0; j < 8; ++j) { float f = (float)vv[j]; s += f * f; }
    }
#pragma unroll
    for (int off = 1; off < 64; off <<= 1) s += __shfl_xor(s, off, 64);

    __shared__ float red[4];
    if ((tid & 63) == 0) red[tid >> 6] = s;
    __syncthreads();
    if (tid == 0) partial[blk] = red[0] + red[1] + red[2] + red[3];
}

// ---------------------------------------------------------------------------
// Kernel 3: ratios + kv_id (replica of _ratios + searchsorted-right)
// ---------------------------------------------------------------------------
__global__ void ratios_kernel(const float* __restrict__ partial,
                              const float* __restrict__ cache,
                              int* __restrict__ kv_id)
{
    if (threadIdx.x != 0 || blockIdx.x != 0) return;
    float mag[8] = {0.f, 0.f, 0.f, 0.f, 0.f, 0.f, 0.f, 0.f};
    for (int b = 0; b < 4; ++b)
        for (int j = 0; j < 8; ++j) {
            float ss = 0.f;
            for (int sl = 0; sl < 8; ++sl) ss += partial[(b * 8 + j) * 8 + sl];
            mag[j] += sqrtf(ss);
        }
    float diff[8], sum = 0.f;
    for (int j = 0; j < 8; ++j) {
        diff[j] = fabsf(cache[j] - mag[j]);
        sum += diff[j];
    }
    int r[8], s = 0;
    for (int j = 0; j < 8; ++j) {
        r[j] = (int)rintf(diff[j] / sum * 16.0f);  // round half to even (jnp.round)
        s += r[j];
    }
    while (s > 16) {
        int jm = 0;
        for (int j = 1; j < 8; ++j) if (r[j] > r[jm]) jm = j;
        r[jm]--; s--;
    }
    while (s < 16) {
        int jm = 0;
        for (int j = 1; j < 8; ++j) if (r[j] < r[jm]) jm = j;
        r[jm]++; s++;
    }
    int cum[8], c = 0;
    for (int j = 0; j < 8; ++j) { c += r[j]; cum[j] = c; }
    for (int h = 0; h < 16; ++h) {
        int j = 0;
        while (j < 7 && cum[j] <= h) j++;  // searchsorted side='right'
        kv_id[h] = j;
    }
}

// ---------------------------------------------------------------------------
// Kernel 4: flash attention, fixed-shift softmax, S^T = mfma(K, Q).
// v5: FOUR q-fragment sets per wave (64 q-rows/wave, 256 q-rows/block).
// K/V LDS fragment reads are identical across sets, so doubling sets halves
// LDS bytes per MFMA -- the round-3 kernel was LDS-BW-bound 2:1.
// P in registers, no cross-lane ops (round-3 verified permutation trick);
// double-buffered K/V, register prefetch, one barrier per K-tile. NO setprio.
// ---------------------------------------------------------------------------
__global__ __launch_bounds__(256, 2) void attn_kernel(
    const __bf16* __restrict__ qw, const __bf16* __restrict__ kw,
    const __bf16* __restrict__ vw, const int* __restrict__ kv_id,
    __bf16* __restrict__ attn_out)
{
    __shared__ __align__(16) __bf16 Kt[2][64 * 72];    // [key][d], pad 72
    __shared__ __align__(16) __bf16 VT[2][64 * 72];    // [d][key], pad 72

    const int bh = blockIdx.y;           // 0..63
    const int b = bh >> 4, h = bh & 15;
    const int q0 = blockIdx.x * 256;
    const int kv = kv_id[h];

    const __bf16* Kg = kw + ((size_t)(b * NKV + kv) * SEQ) * HD;    // [p][d]
    const __bf16* Vg = vw + ((size_t)(b * NKV + kv) * HD) * SEQ;    // [d][p]
    const __bf16* Qg = qw + ((size_t)(b * NH + h) * SEQ + q0) * HD;

    const int tid  = threadIdx.x;
    const int lane = tid & 63, wv = tid >> 6;
    const int l16  = lane & 15, quad = lane >> 4;

    // Four independent Q fragment sets: qrow = 64*wv + 16*s + l16
    bf16x8 qf[4][2];
#pragma unroll
    for (int s = 0; s < 4; ++s) {
        const __bf16* qp = &Qg[(size_t)(64 * wv + 16 * s + l16) * HD];
        qf[s][0] = *(const bf16x8*)&qp[quad * 8];
        qf[s][1] = *(const bf16x8*)&qp[32 + quad * 8];
    }

    float l_acc[4] = {0.f, 0.f, 0.f, 0.f};
    floatx4 o[4][4] = {};

    // staging geometry: thread covers (row = tid>>2, 32B chunk = (tid&3)*16)
    const int row = tid >> 2, cc = (tid & 3) << 4;
    const __bf16* kp = Kg + (size_t)row * HD + cc;    // +4096/tile
    const __bf16* vp = Vg + (size_t)row * SEQ + cc;   // +64/tile

    // prologue: tile 0 -> buf 0
    bf16x8 rk0 = *(const bf16x8*)kp;
    bf16x8 rk1 = *(const bf16x8*)(kp + 8);
    bf16x8 rv0 = *(const bf16x8*)vp;
    bf16x8 rv1 = *(const bf16x8*)(vp + 8);
    {
        __bf16* kd = &Kt[0][row * 72 + cc];
        *(bf16x8*)kd = rk0; *(bf16x8*)(kd + 8) = rk1;
        __bf16* vd = &VT[0][row * 72 + cc];
        *(bf16x8*)vd = rv0; *(bf16x8*)(vd + 8) = rv1;
    }
    __syncthreads();

    for (int kb = 0; kb < 32; ++kb) {
        const int cur = kb & 1;
        const __bf16* Kc = &Kt[cur][0];
        const __bf16* Vc = &VT[cur][0];

        // ---- QK^T: S^T[key][q], all four q-sets share K fragments ----------
        floatx4 sacc[4][4] = {};
        {
            bf16x8 kf[4];
#pragma unroll
            for (int t = 0; t < 4; ++t)
                kf[t] = *(bf16x8*)&Kc[(16 * t + l16) * 72 + quad * 8];
#pragma unroll
            for (int t = 0; t < 4; ++t)
#pragma unroll
                for (int s = 0; s < 4; ++s)
                    sacc[s][t] = __builtin_amdgcn_mfma_f32_16x16x32_bf16(
                        kf[t], qf[s][0], sacc[s][t], 0, 0, 0);
#pragma unroll
            for (int t = 0; t < 4; ++t)
                kf[t] = *(bf16x8*)&Kc[(16 * t + l16) * 72 + 32 + quad * 8];
#pragma unroll
            for (int t = 0; t < 4; ++t)
#pragma unroll
                for (int s = 0; s < 4; ++s)
                    sacc[s][t] = __builtin_amdgcn_mfma_f32_16x16x32_bf16(
                        kf[t], qf[s][1], sacc[s][t], 0, 0, 0);
        }

        // ---- prefetch next K/V tile into registers (hides under softmax+PV)
        if (kb < 31) {
            const __bf16* kn = kp + (size_t)(kb + 1) * (64 * HD);
            const __bf16* vn = vp + (kb + 1) * 64;
            rk0 = *(const bf16x8*)kn;
            rk1 = *(const bf16x8*)(kn + 8);
            rv0 = *(const bf16x8*)vn;
            rv1 = *(const bf16x8*)(vn + 8);
        }

        // ---- softmax (fixed shift) -> per-lane packed PV A-operand ---------
        // lane (l16,quad) reg (t,r) holds P[q=l16][key=16t+4*quad+r].
        // A-op element e <- p[e>>2][e&3]; key order kappa(q,e)=16*(e>>2)+4q+(e&3).
        bf16x8 a0s[4], a1s[4];
#pragma unroll
        for (int s = 0; s < 4; ++s) {
            bf16x8 a0, a1;
#pragma unroll
            for (int r = 0; r < 4; ++r) {
                float e0 = __expf(sacc[s][0][r] - 10.f); l_acc[s] += e0;
                float e1 = __expf(sacc[s][1][r] - 10.f); l_acc[s] += e1;
                float e2 = __expf(sacc[s][2][r] - 10.f); l_acc[s] += e2;
                float e3 = __expf(sacc[s][3][r] - 10.f); l_acc[s] += e3;
                a0[r] = (__bf16)e0; a0[4 + r] = (__bf16)e1;
                a1[r] = (__bf16)e2; a1[4 + r] = (__bf16)e3;
            }
            a0s[s] = a0; a1s[s] = a1;
        }

        // ---- O += P V; B-operand read with matching key permutation,
        //      V fragments read ONCE and reused by all four sets -------------
#pragma unroll
        for (int dt = 0; dt < 4; ++dt) {
            const __bf16* vrow = &Vc[(16 * dt + l16) * 72 + 4 * quad];
            bf16x4 lo0 = *(const bf16x4*)vrow;          // keys  4q..+3
            bf16x4 hi0 = *(const bf16x4*)(vrow + 16);   // keys 16+4q..+3
            bf16x8 vb0 = __builtin_shufflevector(lo0, hi0, 0, 1, 2, 3, 4, 5, 6, 7);
#pragma unroll
            for (int s = 0; s < 4; ++s)
                o[s][dt] = __builtin_amdgcn_mfma_f32_16x16x32_bf16(
                    a0s[s], vb0, o[s][dt], 0, 0, 0);
            bf16x4 lo1 = *(const bf16x4*)(vrow + 32);   // keys 32+4q..+3
            bf16x4 hi1 = *(const bf16x4*)(vrow + 48);   // keys 48+4q..+3
            bf16x8 vb1 = __builtin_shufflevector(lo1, hi1, 0, 1, 2, 3, 4, 5, 6, 7);
#pragma unroll
            for (int s = 0; s < 4; ++s)
                o[s][dt] = __builtin_amdgcn_mfma_f32_16x16x32_bf16(
                    a1s[s], vb1, o[s][dt], 0, 0, 0);
        }

        // ---- write prefetched tile to the other buffer, single barrier ----
        if (kb < 31) {
            __bf16* kd = &Kt[cur ^ 1][row * 72 + cc];
            *(bf16x8*)kd = rk0; *(bf16x8*)(kd + 8) = rk1;
            __bf16* vd = &VT[cur ^ 1][row * 72 + cc];
            *(bf16x8*)vd = rv0; *(bf16x8*)(vd + 8) = rv1;
        }
        __syncthreads();
    }

    // epilogue per set: finish denominator, scale, store [B][P][H][D]
#pragma unroll
    for (int s = 0; s < 4; ++s) {
        float l = l_acc[s];
        l += __shfl_xor(l, 16, 64);
        l += __shfl_xor(l, 32, 64);   // lane holds denom for qrow 64wv+16s+l16
#pragma unroll
        for (int r = 0; r < 4; ++r) {
            float lr = __shfl(l, quad * 4 + r, 64);   // denom of row-offset quad*4+r
            float inv = 1.f / lr;
            int p_ = q0 + 64 * wv + 16 * s + quad * 4 + r;
#pragma unroll
            for (int dt = 0; dt < 4; ++dt) {
                int d = 16 * dt + l16;
                attn_out[(((size_t)b * SEQ + p_) * NH + h) * HD + d] = (__bf16)(o[s][dt][r] * inv);
            }
        }
    }
}

// ---------------------------------------------------------------------------
// Kernel 5: output projection, m97-style (round-3 proven version).
// attn[8192][1024](bf16) @ Wpt(bf16, [c][k]) + bp(f32) -> out (f32)
// ---------------------------------------------------------------------------
__global__ __launch_bounds__(256) void proj_gemm(
    const __bf16* __restrict__ A, const __bf16* __restrict__ Wpt,
    const float* __restrict__ bp, float* __restrict__ out)
{
    __shared__ __align__(16) __bf16 As[128 * 32];
    __shared__ __align__(16) __bf16 Bs[128 * 32];

    const int m0 = blockIdx.y * 128, c0 = blockIdx.x * 128;
    const int tid = threadIdx.x, lane = tid & 63, wv = tid >> 6;
    const int l16 = lane & 15, quad = lane >> 4;
    const int wr = (wv >> 1) * 64, wc = (wv & 1) * 64;

    const int srow = wv * 16 + (lane >> 2);
    const int skc  = (lane & 3) * 8;
    const __bf16* Ag = A   + (size_t)(m0 + srow) * 1024 + skc;
    const __bf16* Bg = Wpt + (size_t)(c0 + srow) * 1024 + skc;
    __bf16* lA = As + wv * 512;
    __bf16* lB = Bs + wv * 512;

    floatx4 acc[4][4] = {};

    for (int k0 = 0; k0 < 1024; k0 += 32) {
        GLDS16(Ag + k0,             lA);
        GLDS16(Ag + k0 + 64 * 1024, lA + 2048);
        GLDS16(Bg + k0,             lB);
        GLDS16(Bg + k0 + 64 * 1024, lB + 2048);
        __syncthreads();

        bf16x8 af[4], bfr[4];
#pragma unroll
        for (int t = 0; t < 4; ++t) {
            af[t]  = *(bf16x8*)&As[(wr + t * 16 + l16) * 32 + quad * 8];
            bfr[t] = *(bf16x8*)&Bs[(wc + t * 16 + l16) * 32 + quad * 8];
        }
#pragma unroll
        for (int mt = 0; mt < 4; ++mt)
#pragma unroll
            for (int nt = 0; nt < 4; ++nt)
                acc[mt][nt] = __builtin_amdgcn_mfma_f32_16x16x32_bf16(
                    af[mt], bfr[nt], acc[mt][nt], 0, 0, 0);
        __syncthreads();
    }

#pragma unroll
    for (int nt = 0; nt < 4; ++nt) {
        int c = c0 + wc + nt * 16 + l16;
        float bias = bp[c];
#pragma unroll
        for (int mt = 0; mt < 4; ++mt)
#pragma unroll
            for (int r = 0; r < 4; ++r) {
                int m = m0 + wr + mt * 16 + quad * 4 + r;
                out[(size_t)m * 1024 + c] = acc[mt][nt][r] + bias;
            }
    }
}

// ---------------------------------------------------------------------------
extern "C" void kernel_launch(void* const* d_in, const int* in_sizes, int n_in,
                              void* d_out, int out_size, void* d_ws, size_t ws_size,
                              hipStream_t stream)
{
    const float* x     = (const float*)d_in[0];
    const float* Wq    = (const float*)d_in[1];
    const float* Wk    = (const float*)d_in[2];
    const float* Wv    = (const float*)d_in[3];
    const float* Wp    = (const float*)d_in[4];
    const float* bp    = (const float*)d_in[5];
    const float* cache = (const float*)d_in[6];
    float* outp = (float*)d_out;

    __bf16* ws = (__bf16*)d_ws;
    __bf16* qw  = ws;                                    // [B][H][P][D]      16 MB
    __bf16* kw  = qw + (size_t)BSZ * NH * SEQ * HD;      // [B][HKV][P][D]     8 MB
    __bf16* vw  = kw + (size_t)BSZ * NKV * SEQ * HD;     // [B][HKV][D][P]     8 MB
    __bf16* at  = vw + (size_t)BSZ * NKV * SEQ * HD;     // [B][P][H*D]       16 MB
    __bf16* xb  = at + (size_t)BSZ * NH * SEQ * HD;      // x in bf16         16 MB
    __bf16* Wt  = xb + (size_t)BSZ * SEQ * DIM;          // [Wq|Wk|Wv]^T bf16  4 MB
    __bf16* Wpt = Wt + (size_t)2048 * 1024;              // Wp^T bf16          2 MB
    float* partial = (float*)(Wpt + (size_t)1024 * 1024);  // 256 floats
    int*   kv_id   = (int*)(partial + 256);                // 16 ints

    prep_kernel<<<2816, 256, 0, stream>>>(x, Wq, Wk, Wv, Wp, xb, Wt, Wpt);
    qkv_gemm<<<dim3(16, 64), 256, 0, stream>>>(xb, Wt, qw, kw, vw);
    ksumsq<<<256, 256, 0, stream>>>(kw, partial);
    ratios_kernel<<<1, 64, 0, stream>>>(partial, cache, kv_id);
    attn_kernel<<<dim3(8, 64), 256, 0, stream>>>(qw, kw, vw, kv_id, at);
    proj_gemm<<<dim3(8, 64), 256, 0, stream>>>(at, Wpt, bp, outp);
}

// Round 7
// 286.426 us; speedup vs baseline: 1.1533x; 1.0079x over previous
//
#include <hip/hip_runtime.h>

typedef __bf16 bf16x8 __attribute__((ext_vector_type(8)));
typedef __bf16 bf16x4 __attribute__((ext_vector_type(4)));
typedef float floatx4 __attribute__((ext_vector_type(4)));

// Sizes (fixed): B=4, P=2048, DIM=1024, H=16, HKV=8, D=64
#define BSZ 4
#define SEQ 2048
#define DIM 1024
#define NH 16
#define NKV 8
#define HD 64

// Q pre-scale: D^-0.5 * log2(e), so QK^T accumulates s*log2e directly.
#define QSCALE 0.18033688011112042f
// C-init for QK^T accumulator: -10*log2(e)  ->  p = 2^(sacc) == exp(s-10)
#define CSHIFT -14.426950408889634f

#if __has_builtin(__builtin_amdgcn_exp2f)
#define EXP2(x) __builtin_amdgcn_exp2f(x)
#else
#define EXP2(x) exp2f(x)
#endif

// async global->LDS, 16B per lane; LDS dest = wave-uniform base + lane*16
#define GLDS16(g, l) __builtin_amdgcn_global_load_lds(                        \
    (const __attribute__((address_space(1))) void*)(g),                       \
    (__attribute__((address_space(3))) void*)(l), 16, 0, 0)

// ---------------------------------------------------------------------------
// Kernel 0: merged prep.
//   blocks [0,2048): x (f32) -> xb (bf16)
//   blocks [2048,2816): W transpose to bf16 [N][K]
//     Wt rows 0..1023 = Wq^T, 1024..1535 = Wk^T, 1536..2047 = Wv^T; Wpt = Wp^T
// ---------------------------------------------------------------------------
__global__ __launch_bounds__(256) void prep_kernel(
    const float* __restrict__ x,
    const float* __restrict__ Wq, const float* __restrict__ Wk,
    const float* __restrict__ Wv, const float* __restrict__ Wp,
    __bf16* __restrict__ xb, __bf16* __restrict__ Wt, __bf16* __restrict__ Wpt)
{
    __shared__ __bf16 T[64][72];   // [c][k], pad 72
    const int bid = blockIdx.x;
    const int tid = threadIdx.x;

    if (bid < 2048) {
        size_t i = ((size_t)bid * 256 + tid) * 16;
#pragma unroll
        for (int q = 0; q < 2; ++q) {
            float4 a = *(const float4*)&x[i + q * 8];
            float4 b = *(const float4*)&x[i + q * 8 + 4];
            bf16x8 o;
            o[0] = (__bf16)a.x; o[1] = (__bf16)a.y; o[2] = (__bf16)a.z; o[3] = (__bf16)a.w;
            o[4] = (__bf16)b.x; o[5] = (__bf16)b.y; o[6] = (__bf16)b.z; o[7] = (__bf16)b.w;
            *(bf16x8*)&xb[i + q * 8] = o;
        }
        return;
    }

    const int t  = bid - 2048;
    const int k0 = (t & 15) * 64;
    const int cg = (t >> 4) * 64;

    const float* W; int ldn, cl, orow; __bf16* out;
    if (cg < 1024)      { W = Wq; ldn = 1024; cl = cg;        out = Wt;  orow = cg; }
    else if (cg < 1536) { W = Wk; ldn = 512;  cl = cg - 1024; out = Wt;  orow = cg; }
    else if (cg < 2048) { W = Wv; ldn = 512;  cl = cg - 1536; out = Wt;  orow = cg; }
    else                { W = Wp; ldn = 1024; cl = cg - 2048; out = Wpt; orow = cg - 2048; }

    const int kr = tid >> 2;            // tile row (k), 0..63
    const int cq = (tid & 3) * 16;      // tile col base (c)
#pragma unroll
    for (int j = 0; j < 4; ++j) {
        float4 f = *(const float4*)&W[(size_t)(k0 + kr) * ldn + cl + cq + j * 4];
        T[cq + j * 4 + 0][kr] = (__bf16)f.x;
        T[cq + j * 4 + 1][kr] = (__bf16)f.y;
        T[cq + j * 4 + 2][kr] = (__bf16)f.z;
        T[cq + j * 4 + 3][kr] = (__bf16)f.w;
    }
    __syncthreads();
#pragma unroll
    for (int j = 0; j < 2; ++j) {
        int ch = tid * 2 + j;                 // 512 chunks of 16B
        int c = ch >> 3, kc = (ch & 7) * 8;
        *(bf16x8*)&out[(size_t)(orow + c) * 1024 + k0 + kc] = *(bf16x8*)&T[c][kc];
    }
}

// 2-phase double-buffered staging: issue next K-tile's global_load_lds into
// the other buffer BEFORE computing the current one; one barrier per K-step.
// Buffer read at t-1 is safe to overwrite at t (barrier t-1 drained lgkm);
// buffer staged at t-1 is ready at t (barrier t-1 drained vmcnt).
// K=1024, BK=32 -> 32 iterations (round-6 bug: ran only 16).
#define GSTAGE(bi, kk)                                                        \
    {                                                                         \
        GLDS16(Ag + (kk),             &As[bi][wv * 512]);                     \
        GLDS16(Ag + (kk) + 64 * 1024, &As[bi][2048 + wv * 512]);              \
        GLDS16(Bg + (kk),             &Bs[bi][wv * 512]);                     \
        GLDS16(Bg + (kk) + 64 * 1024, &Bs[bi][2048 + wv * 512]);              \
    }

// ---------------------------------------------------------------------------
// Kernel 1: fused QKV projection, 128x128 tile, BK=32, 2-phase dbuf.
// xb(bf16) @ Wt(bf16, [c][k]) -> q,k (bf16 [B][H][P][D]) and v TRANSPOSED
// (bf16 [B][HKV][D][P]).  q scaled by 0.125*log2e (see QSCALE).
// ---------------------------------------------------------------------------
__global__ __launch_bounds__(256) void qkv_gemm(
    const __bf16* __restrict__ xb, const __bf16* __restrict__ Wt,
    __bf16* __restrict__ qw, __bf16* __restrict__ kw, __bf16* __restrict__ vw)
{
    __shared__ __align__(16) __bf16 As[2][128 * 32];   // [m][kk] linear, dbuf
    __shared__ __align__(16) __bf16 Bs[2][128 * 32];   // [c][kk] linear, dbuf

    const int m0 = blockIdx.y * 128;
    const int c0 = blockIdx.x * 128;

    const int tid  = threadIdx.x;
    const int lane = tid & 63, wv = tid >> 6;
    const int l16  = lane & 15, quad = lane >> 4;
    const int wr = (wv >> 1) * 64, wc = (wv & 1) * 64;

    const int srow = wv * 16 + (lane >> 2);
    const int skc  = (lane & 3) * 8;
    const __bf16* Ag = xb + (size_t)(m0 + srow) * 1024 + skc;
    const __bf16* Bg = Wt + (size_t)(c0 + srow) * 1024 + skc;

    floatx4 acc[4][4] = {};

    GSTAGE(0, 0);
    __syncthreads();

    for (int t = 0; t < 32; ++t) {
        const int cur = t & 1;
        if (t < 31) GSTAGE(cur ^ 1, (t + 1) * 32);

        bf16x8 af[4], bfr[4];
#pragma unroll
        for (int tt = 0; tt < 4; ++tt) {
            af[tt]  = *(bf16x8*)&As[cur][(wr + tt * 16 + l16) * 32 + quad * 8];
            bfr[tt] = *(bf16x8*)&Bs[cur][(wc + tt * 16 + l16) * 32 + quad * 8];
        }
#pragma unroll
        for (int mt = 0; mt < 4; ++mt)
#pragma unroll
            for (int nt = 0; nt < 4; ++nt)
                acc[mt][nt] = __builtin_amdgcn_mfma_f32_16x16x32_bf16(
                    af[mt], bfr[nt], acc[mt][nt], 0, 0, 0);
        __syncthreads();
    }

#pragma unroll
    for (int mt = 0; mt < 4; ++mt) {
#pragma unroll
        for (int nt = 0; nt < 4; ++nt) {
#pragma unroll
            for (int r = 0; r < 4; ++r) {
                int m = m0 + wr + mt * 16 + quad * 4 + r;
                int c = c0 + wc + nt * 16 + l16;
                int bb = m >> 11, p = m & 2047;
                float val = acc[mt][nt][r];
                if (c < 1024) {
                    int h = c >> 6, d = c & 63;
                    qw[(((size_t)bb * NH + h) * SEQ + p) * HD + d] = (__bf16)(val * QSCALE);
                } else if (c < 1536) {
                    int cc = c - 1024, hh = cc >> 6, d = cc & 63;
                    kw[(((size_t)bb * NKV + hh) * SEQ + p) * HD + d] = (__bf16)val;
                } else {
                    int cc = c - 1536, hh = cc >> 6, d = cc & 63;
                    vw[(((size_t)bb * NKV + hh) * HD + d) * SEQ + p] = (__bf16)val;
                }
            }
        }
    }
}

// ---------------------------------------------------------------------------
// Kernel 2: partial sum-of-squares of k. 256 blocks: (b*8+kv)*8 + slice.
// ---------------------------------------------------------------------------
__global__ __launch_bounds__(256) void ksumsq(const __bf16* __restrict__ kw,
                                              float* __restrict__ partial)
{
    const int blk = blockIdx.x;
    const __bf16* base = kw + (size_t)(blk >> 3) * (SEQ * HD)
                            + (size_t)(blk & 7) * (SEQ * HD / 8);
    const int tid = threadIdx.x;

    float s = 0.f;
#pragma unroll
    for (int i = tid * 8; i < SEQ * HD / 8; i += 256 * 8) {
        bf16x8 vv = *(const bf16x8*)&base[i];
#pragma unroll
        for (int j = 0; j < 8; ++j) { float f = (float)vv[j]; s += f * f; }
    }
#pragma unroll
    for (int off = 1; off < 64; off <<= 1) s += __shfl_xor(s, off, 64);

    __shared__ float red[4];
    if ((tid & 63) == 0) red[tid >> 6] = s;
    __syncthreads();
    if (tid == 0) partial[blk] = red[0] + red[1] + red[2] + red[3];
}

// ---------------------------------------------------------------------------
// Kernel 3: ratios + kv_id (replica of _ratios + searchsorted-right)
// ---------------------------------------------------------------------------
__global__ void ratios_kernel(const float* __restrict__ partial,
                              const float* __restrict__ cache,
                              int* __restrict__ kv_id)
{
    if (threadIdx.x != 0 || blockIdx.x != 0) return;
    float mag[8] = {0.f, 0.f, 0.f, 0.f, 0.f, 0.f, 0.f, 0.f};
    for (int b = 0; b < 4; ++b)
        for (int j = 0; j < 8; ++j) {
            float ss = 0.f;
            for (int sl = 0; sl < 8; ++sl) ss += partial[(b * 8 + j) * 8 + sl];
            mag[j] += sqrtf(ss);
        }
    float diff[8], sum = 0.f;
    for (int j = 0; j < 8; ++j) {
        diff[j] = fabsf(cache[j] - mag[j]);
        sum += diff[j];
    }
    int r[8], s = 0;
    for (int j = 0; j < 8; ++j) {
        r[j] = (int)rintf(diff[j] / sum * 16.0f);  // round half to even (jnp.round)
        s += r[j];
    }
    while (s > 16) {
        int jm = 0;
        for (int j = 1; j < 8; ++j) if (r[j] > r[jm]) jm = j;
        r[jm]--; s--;
    }
    while (s < 16) {
        int jm = 0;
        for (int j = 1; j < 8; ++j) if (r[j] < r[jm]) jm = j;
        r[jm]++; s++;
    }
    int cum[8], c = 0;
    for (int j = 0; j < 8; ++j) { c += r[j]; cum[j] = c; }
    for (int h = 0; h < 16; ++h) {
        int j = 0;
        while (j < 7 && cum[j] <= h) j++;  // searchsorted side='right'
        kv_id[h] = j;
    }
}

// ---------------------------------------------------------------------------
// Kernel 4: flash attention, v6 (retained from round 6; its failure was the
// GEMM trip-count bug, not this kernel).
// - Q pre-scaled by log2e and QK^T accumulator C-initialized to -10*log2e:
//   p = v_exp_f32(sacc) directly (one VALU op per score).
// - denominator via MFMA row-sum with an all-ones B fragment (ol[s]).
// - otherwise identical to round-5 (4 q-sets/wave, P in registers with the
//   matching-key-permutation PV, double-buffered K/V, one barrier/K-tile).
// ---------------------------------------------------------------------------
__global__ __launch_bounds__(256, 2) void attn_kernel(
    const __bf16* __restrict__ qw, const __bf16* __restrict__ kw,
    const __bf16* __restrict__ vw, const int* __restrict__ kv_id,
    __bf16* __restrict__ attn_out)
{
    __shared__ __align__(16) __bf16 Kt[2][64 * 72];    // [key][d], pad 72
    __shared__ __align__(16) __bf16 VT[2][64 * 72];    // [d][key], pad 72

    const int bh = blockIdx.y;           // 0..63
    const int b = bh >> 4, h = bh & 15;
    const int q0 = blockIdx.x * 256;
    const int kv = kv_id[h];

    const __bf16* Kg = kw + ((size_t)(b * NKV + kv) * SEQ) * HD;    // [p][d]
    const __bf16* Vg = vw + ((size_t)(b * NKV + kv) * HD) * SEQ;    // [d][p]
    const __bf16* Qg = qw + ((size_t)(b * NH + h) * SEQ + q0) * HD;

    const int tid  = threadIdx.x;
    const int lane = tid & 63, wv = tid >> 6;
    const int l16  = lane & 15, quad = lane >> 4;

    // Four independent Q fragment sets: qrow = 64*wv + 16*s + l16
    bf16x8 qf[4][2];
#pragma unroll
    for (int s = 0; s < 4; ++s) {
        const __bf16* qp = &Qg[(size_t)(64 * wv + 16 * s + l16) * HD];
        qf[s][0] = *(const bf16x8*)&qp[quad * 8];
        qf[s][1] = *(const bf16x8*)&qp[32 + quad * 8];
    }

    bf16x8 vones;
#pragma unroll
    for (int j = 0; j < 8; ++j) vones[j] = (__bf16)1.0f;

    floatx4 o[4][4] = {};
    floatx4 ol[4] = {};     // denominators via MFMA row-sum

    // staging geometry: thread covers (row = tid>>2, 32B chunk = (tid&3)*16)
    const int row = tid >> 2, cc = (tid & 3) << 4;
    const __bf16* kp = Kg + (size_t)row * HD + cc;    // +4096/tile
    const __bf16* vp = Vg + (size_t)row * SEQ + cc;   // +64/tile

    // prologue: tile 0 -> buf 0
    bf16x8 rk0 = *(const bf16x8*)kp;
    bf16x8 rk1 = *(const bf16x8*)(kp + 8);
    bf16x8 rv0 = *(const bf16x8*)vp;
    bf16x8 rv1 = *(const bf16x8*)(vp + 8);
    {
        __bf16* kd = &Kt[0][row * 72 + cc];
        *(bf16x8*)kd = rk0; *(bf16x8*)(kd + 8) = rk1;
        __bf16* vd = &VT[0][row * 72 + cc];
        *(bf16x8*)vd = rv0; *(bf16x8*)(vd + 8) = rv1;
    }
    __syncthreads();

    const floatx4 cinit = {CSHIFT, CSHIFT, CSHIFT, CSHIFT};

    for (int kb = 0; kb < 32; ++kb) {
        const int cur = kb & 1;
        const __bf16* Kc = &Kt[cur][0];
        const __bf16* Vc = &VT[cur][0];

        // ---- QK^T: S^T[key][q] * log2e - 10*log2e, C-initialized ----------
        floatx4 sacc[4][4];
#pragma unroll
        for (int s = 0; s < 4; ++s)
#pragma unroll
            for (int t = 0; t < 4; ++t) sacc[s][t] = cinit;
        {
            bf16x8 kf[4];
#pragma unroll
            for (int t = 0; t < 4; ++t)
                kf[t] = *(bf16x8*)&Kc[(16 * t + l16) * 72 + quad * 8];
#pragma unroll
            for (int t = 0; t < 4; ++t)
#pragma unroll
                for (int s = 0; s < 4; ++s)
                    sacc[s][t] = __builtin_amdgcn_mfma_f32_16x16x32_bf16(
                        kf[t], qf[s][0], sacc[s][t], 0, 0, 0);
#pragma unroll
            for (int t = 0; t < 4; ++t)
                kf[t] = *(bf16x8*)&Kc[(16 * t + l16) * 72 + 32 + quad * 8];
#pragma unroll
            for (int t = 0; t < 4; ++t)
#pragma unroll
                for (int s = 0; s < 4; ++s)
                    sacc[s][t] = __builtin_amdgcn_mfma_f32_16x16x32_bf16(
                        kf[t], qf[s][1], sacc[s][t], 0, 0, 0);
        }

        // ---- prefetch next K/V tile into registers (hides under softmax+PV)
        if (kb < 31) {
            const __bf16* kn = kp + (size_t)(kb + 1) * (64 * HD);
            const __bf16* vn = vp + (kb + 1) * 64;
            rk0 = *(const bf16x8*)kn;
            rk1 = *(const bf16x8*)(kn + 8);
            rv0 = *(const bf16x8*)vn;
            rv1 = *(const bf16x8*)(vn + 8);
        }

        // ---- softmax: p = 2^sacc, one v_exp per score ----------------------
        // lane (l16,quad) reg (t,r) holds P[q=l16][key=16t+4*quad+r].
        // A-op element e <- p[e>>2][e&3]; key order kappa(q,e)=16*(e>>2)+4q+(e&3).
        bf16x8 a0s[4], a1s[4];
#pragma unroll
        for (int s = 0; s < 4; ++s) {
            bf16x8 a0, a1;
#pragma unroll
            for (int r = 0; r < 4; ++r) {
                float e0 = EXP2(sacc[s][0][r]);
                float e1 = EXP2(sacc[s][1][r]);
                float e2 = EXP2(sacc[s][2][r]);
                float e3 = EXP2(sacc[s][3][r]);
                a0[r] = (__bf16)e0; a0[4 + r] = (__bf16)e1;
                a1[r] = (__bf16)e2; a1[4 + r] = (__bf16)e3;
            }
            a0s[s] = a0; a1s[s] = a1;
        }

        // ---- denominators: ol[s] += rowsum(P) via ones-B MFMA --------------
#pragma unroll
        for (int s = 0; s < 4; ++s) {
            ol[s] = __builtin_amdgcn_mfma_f32_16x16x32_bf16(a0s[s], vones, ol[s], 0, 0, 0);
            ol[s] = __builtin_amdgcn_mfma_f32_16x16x32_bf16(a1s[s], vones, ol[s], 0, 0, 0);
        }

        // ---- O += P V; B-operand read with matching key permutation,
        //      V fragments read ONCE and reused by all four sets -------------
#pragma unroll
        for (int dt = 0; dt < 4; ++dt) {
            const __bf16* vrow = &Vc[(16 * dt + l16) * 72 + 4 * quad];
            bf16x4 lo0 = *(const bf16x4*)vrow;          // keys  4q..+3
            bf16x4 hi0 = *(const bf16x4*)(vrow + 16);   // keys 16+4q..+3
            bf16x8 vb0 = __builtin_shufflevector(lo0, hi0, 0, 1, 2, 3, 4, 5, 6, 7);
#pragma unroll
            for (int s = 0; s < 4; ++s)
                o[s][dt] = __builtin_amdgcn_mfma_f32_16x16x32_bf16(
                    a0s[s], vb0, o[s][dt], 0, 0, 0);
            bf16x4 lo1 = *(const bf16x4*)(vrow + 32);   // keys 32+4q..+3
            bf16x4 hi1 = *(const bf16x4*)(vrow + 48);   // keys 48+4q..+3
            bf16x8 vb1 = __builtin_shufflevector(lo1, hi1, 0, 1, 2, 3, 4, 5, 6, 7);
#pragma unroll
            for (int s = 0; s < 4; ++s)
                o[s][dt] = __builtin_amdgcn_mfma_f32_16x16x32_bf16(
                    a1s[s], vb1, o[s][dt], 0, 0, 0);
        }

        // ---- write prefetched tile to the other buffer, single barrier ----
        if (kb < 31) {
            __bf16* kd = &Kt[cur ^ 1][row * 72 + cc];
            *(bf16x8*)kd = rk0; *(bf16x8*)(kd + 8) = rk1;
            __bf16* vd = &VT[cur ^ 1][row * 72 + cc];
            *(bf16x8*)vd = rv0; *(bf16x8*)(vd + 8) = rv1;
        }
        __syncthreads();
    }

    // epilogue per set: denom from ol (same C row mapping as o), store
#pragma unroll
    for (int s = 0; s < 4; ++s) {
#pragma unroll
        for (int r = 0; r < 4; ++r) {
            float inv = 1.f / ol[s][r];
            int p_ = q0 + 64 * wv + 16 * s + quad * 4 + r;
#pragma unroll
            for (int dt = 0; dt < 4; ++dt) {
                int d = 16 * dt + l16;
                attn_out[(((size_t)b * SEQ + p_) * NH + h) * HD + d] = (__bf16)(o[s][dt][r] * inv);
            }
        }
    }
}

// ---------------------------------------------------------------------------
// Kernel 5: output projection, 128x128 tile, BK=32, 2-phase dbuf.
// attn[8192][1024](bf16) @ Wpt(bf16, [c][k]) + bp(f32) -> out (f32)
// ---------------------------------------------------------------------------
__global__ __launch_bounds__(256) void proj_gemm(
    const __bf16* __restrict__ A, const __bf16* __restrict__ Wpt,
    const float* __restrict__ bp, float* __restrict__ out)
{
    __shared__ __align__(16) __bf16 As[2][128 * 32];
    __shared__ __align__(16) __bf16 Bs[2][128 * 32];

    const int m0 = blockIdx.y * 128, c0 = blockIdx.x * 128;
    const int tid = threadIdx.x, lane = tid & 63, wv = tid >> 6;
    const int l16 = lane & 15, quad = lane >> 4;
    const int wr = (wv >> 1) * 64, wc = (wv & 1) * 64;

    const int srow = wv * 16 + (lane >> 2);
    const int skc  = (lane & 3) * 8;
    const __bf16* Ag = A   + (size_t)(m0 + srow) * 1024 + skc;
    const __bf16* Bg = Wpt + (size_t)(c0 + srow) * 1024 + skc;

    floatx4 acc[4][4] = {};

    GSTAGE(0, 0);
    __syncthreads();

    for (int t = 0; t < 32; ++t) {
        const int cur = t & 1;
        if (t < 31) GSTAGE(cur ^ 1, (t + 1) * 32);

        bf16x8 af[4], bfr[4];
#pragma unroll
        for (int tt = 0; tt < 4; ++tt) {
            af[tt]  = *(bf16x8*)&As[cur][(wr + tt * 16 + l16) * 32 + quad * 8];
            bfr[tt] = *(bf16x8*)&Bs[cur][(wc + tt * 16 + l16) * 32 + quad * 8];
        }
#pragma unroll
        for (int mt = 0; mt < 4; ++mt)
#pragma unroll
            for (int nt = 0; nt < 4; ++nt)
                acc[mt][nt] = __builtin_amdgcn_mfma_f32_16x16x32_bf16(
                    af[mt], bfr[nt], acc[mt][nt], 0, 0, 0);
        __syncthreads();
    }

#pragma unroll
    for (int nt = 0; nt < 4; ++nt) {
        int c = c0 + wc + nt * 16 + l16;
        float bias = bp[c];
#pragma unroll
        for (int mt = 0; mt < 4; ++mt)
#pragma unroll
            for (int r = 0; r < 4; ++r) {
                int m = m0 + wr + mt * 16 + quad * 4 + r;
                out[(size_t)m * 1024 + c] = acc[mt][nt][r] + bias;
            }
    }
}

// ---------------------------------------------------------------------------
extern "C" void kernel_launch(void* const* d_in, const int* in_sizes, int n_in,
                              void* d_out, int out_size, void* d_ws, size_t ws_size,
                              hipStream_t stream)
{
    const float* x     = (const float*)d_in[0];
    const float* Wq    = (const float*)d_in[1];
    const float* Wk    = (const float*)d_in[2];
    const float* Wv    = (const float*)d_in[3];
    const float* Wp    = (const float*)d_in[4];
    const float* bp    = (const float*)d_in[5];
    const float* cache = (const float*)d_in[6];
    float* outp = (float*)d_out;

    __bf16* ws = (__bf16*)d_ws;
    __bf16* qw  = ws;                                    // [B][H][P][D]      16 MB
    __bf16* kw  = qw + (size_t)BSZ * NH * SEQ * HD;      // [B][HKV][P][D]     8 MB
    __bf16* vw  = kw + (size_t)BSZ * NKV * SEQ * HD;     // [B][HKV][D][P]     8 MB
    __bf16* at  = vw + (size_t)BSZ * NKV * SEQ * HD;     // [B][P][H*D]       16 MB
    __bf16* xb  = at + (size_t)BSZ * NH * SEQ * HD;      // x in bf16         16 MB
    __bf16* Wt  = xb + (size_t)BSZ * SEQ * DIM;          // [Wq|Wk|Wv]^T bf16  4 MB
    __bf16* Wpt = Wt + (size_t)2048 * 1024;              // Wp^T bf16          2 MB
    float* partial = (float*)(Wpt + (size_t)1024 * 1024);  // 256 floats
    int*   kv_id   = (int*)(partial + 256);                // 16 ints

    prep_kernel<<<2816, 256, 0, stream>>>(x, Wq, Wk, Wv, Wp, xb, Wt, Wpt);
    qkv_gemm<<<dim3(16, 64), 256, 0, stream>>>(xb, Wt, qw, kw, vw);
    ksumsq<<<256, 256, 0, stream>>>(kw, partial);
    ratios_kernel<<<1, 64, 0, stream>>>(partial, cache, kv_id);
    attn_kernel<<<dim3(8, 64), 256, 0, stream>>>(qw, kw, vw, kv_id, at);
    proj_gemm<<<dim3(8, 64), 256, 0, stream>>>(at, Wpt, bp, outp);
}

// Round 8
// 265.786 us; speedup vs baseline: 1.2428x; 1.0777x over previous
//
#include <hip/hip_runtime.h>

typedef __bf16 bf16x8 __attribute__((ext_vector_type(8)));
typedef __bf16 bf16x4 __attribute__((ext_vector_type(4)));
typedef float floatx4 __attribute__((ext_vector_type(4)));

// Sizes (fixed): B=4, P=2048, DIM=1024, H=16, HKV=8, D=64
#define BSZ 4
#define SEQ 2048
#define DIM 1024
#define NH 16
#define NKV 8
#define HD 64

// Q pre-scale: D^-0.5 * log2(e), so QK^T accumulates s*log2e directly.
#define QSCALE 0.18033688011112042f
// C-init for QK^T accumulator: -10*log2(e)  ->  p = 2^(sacc) == exp(s-10)
#define CSHIFT -14.426950408889634f

#if __has_builtin(__builtin_amdgcn_exp2f)
#define EXP2(x) __builtin_amdgcn_exp2f(x)
#else
#define EXP2(x) exp2f(x)
#endif

// async global->LDS, 16B per lane; LDS dest = wave-uniform base + lane*16
#define GLDS16(g, l) __builtin_amdgcn_global_load_lds(                        \
    (const __attribute__((address_space(1))) void*)(g),                       \
    (__attribute__((address_space(3))) void*)(l), 16, 0, 0)

// ---------------------------------------------------------------------------
// Kernel 0: merged prep.
//   blocks [0,2048): x (f32) -> xb (bf16)
//   blocks [2048,2816): W transpose to bf16 [N][K]
//     Wt rows 0..1023 = Wq^T, 1024..1535 = Wk^T, 1536..2047 = Wv^T; Wpt = Wp^T
// ---------------------------------------------------------------------------
__global__ __launch_bounds__(256) void prep_kernel(
    const float* __restrict__ x,
    const float* __restrict__ Wq, const float* __restrict__ Wk,
    const float* __restrict__ Wv, const float* __restrict__ Wp,
    __bf16* __restrict__ xb, __bf16* __restrict__ Wt, __bf16* __restrict__ Wpt)
{
    __shared__ __bf16 T[64][72];   // [c][k], pad 72
    const int bid = blockIdx.x;
    const int tid = threadIdx.x;

    if (bid < 2048) {
        size_t i = ((size_t)bid * 256 + tid) * 16;
#pragma unroll
        for (int q = 0; q < 2; ++q) {
            float4 a = *(const float4*)&x[i + q * 8];
            float4 b = *(const float4*)&x[i + q * 8 + 4];
            bf16x8 o;
            o[0] = (__bf16)a.x; o[1] = (__bf16)a.y; o[2] = (__bf16)a.z; o[3] = (__bf16)a.w;
            o[4] = (__bf16)b.x; o[5] = (__bf16)b.y; o[6] = (__bf16)b.z; o[7] = (__bf16)b.w;
            *(bf16x8*)&xb[i + q * 8] = o;
        }
        return;
    }

    const int t  = bid - 2048;
    const int k0 = (t & 15) * 64;
    const int cg = (t >> 4) * 64;

    const float* W; int ldn, cl, orow; __bf16* out;
    if (cg < 1024)      { W = Wq; ldn = 1024; cl = cg;        out = Wt;  orow = cg; }
    else if (cg < 1536) { W = Wk; ldn = 512;  cl = cg - 1024; out = Wt;  orow = cg; }
    else if (cg < 2048) { W = Wv; ldn = 512;  cl = cg - 1536; out = Wt;  orow = cg; }
    else                { W = Wp; ldn = 1024; cl = cg - 2048; out = Wpt; orow = cg - 2048; }

    const int kr = tid >> 2;            // tile row (k), 0..63
    const int cq = (tid & 3) * 16;      // tile col base (c)
#pragma unroll
    for (int j = 0; j < 4; ++j) {
        float4 f = *(const float4*)&W[(size_t)(k0 + kr) * ldn + cl + cq + j * 4];
        T[cq + j * 4 + 0][kr] = (__bf16)f.x;
        T[cq + j * 4 + 1][kr] = (__bf16)f.y;
        T[cq + j * 4 + 2][kr] = (__bf16)f.z;
        T[cq + j * 4 + 3][kr] = (__bf16)f.w;
    }
    __syncthreads();
#pragma unroll
    for (int j = 0; j < 2; ++j) {
        int ch = tid * 2 + j;                 // 512 chunks of 16B
        int c = ch >> 3, kc = (ch & 7) * 8;
        *(bf16x8*)&out[(size_t)(orow + c) * 1024 + k0 + kc] = *(bf16x8*)&T[c][kc];
    }
}

// ---------------------------------------------------------------------------
// Kernel 1: fused QKV projection, 128x128 tile, BK=32, 2-phase dbuf.
// xb(bf16) @ Wt(bf16, [c][k]) -> q,k (bf16 [B][H][P][D]) and v TRANSPOSED
// (bf16 [B][HKV][D][P]).  q scaled by 0.125*log2e.
// v8: V-region epilogue transposes the 128x128 tile through LDS and stores
// coalesced bf16x8 rows along p (was: 2-byte scatter at 4KB stride = ~15us
// store tail on 1/4 of blocks).  As/Bs/T share dynamic LDS (34816 B).
// ---------------------------------------------------------------------------
#define QSTAGE(bi, kk)                                                        \
    {                                                                         \
        GLDS16(Ag + (kk),             Asb + (bi) * 4096 + wv * 512);          \
        GLDS16(Ag + (kk) + 64 * 1024, Asb + (bi) * 4096 + 2048 + wv * 512);   \
        GLDS16(Bg + (kk),             Bsb + (bi) * 4096 + wv * 512);          \
        GLDS16(Bg + (kk) + 64 * 1024, Bsb + (bi) * 4096 + 2048 + wv * 512);   \
    }

__global__ __launch_bounds__(256) void qkv_gemm(
    const __bf16* __restrict__ xb, const __bf16* __restrict__ Wt,
    __bf16* __restrict__ qw, __bf16* __restrict__ kw, __bf16* __restrict__ vw)
{
    extern __shared__ __align__(16) __bf16 smem[];   // 34816 B
    __bf16* Asb = smem;            // As[bi] = Asb + bi*4096   (16 KB)
    __bf16* Bsb = smem + 8192;     // Bs[bi] = Bsb + bi*4096   (16 KB)
    // T (V transpose, 128*136 elems = 34816 B) reuses smem after the K-loop.

    const int m0 = blockIdx.y * 128;
    const int c0 = blockIdx.x * 128;

    const int tid  = threadIdx.x;
    const int lane = tid & 63, wv = tid >> 6;
    const int l16  = lane & 15, quad = lane >> 4;
    const int wr = (wv >> 1) * 64, wc = (wv & 1) * 64;

    const int srow = wv * 16 + (lane >> 2);
    const int skc  = (lane & 3) * 8;
    const __bf16* Ag = xb + (size_t)(m0 + srow) * 1024 + skc;
    const __bf16* Bg = Wt + (size_t)(c0 + srow) * 1024 + skc;

    floatx4 acc[4][4] = {};

    QSTAGE(0, 0);
    __syncthreads();

    for (int t = 0; t < 32; ++t) {
        const int cur = t & 1;
        if (t < 31) QSTAGE(cur ^ 1, (t + 1) * 32);

        bf16x8 af[4], bfr[4];
#pragma unroll
        for (int tt = 0; tt < 4; ++tt) {
            af[tt]  = *(bf16x8*)&Asb[cur * 4096 + (wr + tt * 16 + l16) * 32 + quad * 8];
            bfr[tt] = *(bf16x8*)&Bsb[cur * 4096 + (wc + tt * 16 + l16) * 32 + quad * 8];
        }
#pragma unroll
        for (int mt = 0; mt < 4; ++mt)
#pragma unroll
            for (int nt = 0; nt < 4; ++nt)
                acc[mt][nt] = __builtin_amdgcn_mfma_f32_16x16x32_bf16(
                    af[mt], bfr[nt], acc[mt][nt], 0, 0, 0);
        __syncthreads();
    }

    const int bb = m0 >> 11;          // regions are block-uniform (c0 mult of 128)
    if (c0 < 1536) {
        // Q / K regions: stores along d are coalesced (lane = d)
#pragma unroll
        for (int mt = 0; mt < 4; ++mt) {
#pragma unroll
            for (int nt = 0; nt < 4; ++nt) {
#pragma unroll
                for (int r = 0; r < 4; ++r) {
                    int m = m0 + wr + mt * 16 + quad * 4 + r;
                    int c = c0 + wc + nt * 16 + l16;
                    int p = m & 2047;
                    float val = acc[mt][nt][r];
                    if (c < 1024) {
                        int h = c >> 6, d = c & 63;
                        qw[(((size_t)bb * NH + h) * SEQ + p) * HD + d] = (__bf16)(val * QSCALE);
                    } else {
                        int cc = c - 1024, hh = cc >> 6, d = cc & 63;
                        kw[(((size_t)bb * NKV + hh) * SEQ + p) * HD + d] = (__bf16)val;
                    }
                }
            }
        }
    } else {
        // V region: transpose through LDS, then coalesced stores along p.
        __bf16* T = smem;   // [c_local][m_local], row stride 136 (16B-aligned rows)
#pragma unroll
        for (int mt = 0; mt < 4; ++mt)
#pragma unroll
            for (int nt = 0; nt < 4; ++nt) {
                bf16x4 pv;
#pragma unroll
                for (int r = 0; r < 4; ++r) pv[r] = (__bf16)acc[mt][nt][r];
                *(bf16x4*)&T[(wc + nt * 16 + l16) * 136 + wr + mt * 16 + quad * 4] = pv;
            }
        __syncthreads();

        const int c_l = tid >> 1, half = tid & 1;
        const int cc = c0 - 1536 + c_l, hh = cc >> 6, d = cc & 63;
        const int p0 = (m0 & 2047) + half * 64;
        __bf16* dst = &vw[((size_t)(bb * NKV + hh) * HD + d) * SEQ + p0];
        const __bf16* src = &T[c_l * 136 + half * 64];
#pragma unroll
        for (int i = 0; i < 8; ++i)
            *(bf16x8*)&dst[i * 8] = *(const bf16x8*)&src[i * 8];
    }
}

// ---------------------------------------------------------------------------
// Kernel 2: partial sum-of-squares of k. 256 blocks: (b*8+kv)*8 + slice.
// ---------------------------------------------------------------------------
__global__ __launch_bounds__(256) void ksumsq(const __bf16* __restrict__ kw,
                                              float* __restrict__ partial)
{
    const int blk = blockIdx.x;
    const __bf16* base = kw + (size_t)(blk >> 3) * (SEQ * HD)
                            + (size_t)(blk & 7) * (SEQ * HD / 8);
    const int tid = threadIdx.x;

    float s = 0.f;
#pragma unroll
    for (int i = tid * 8; i < SEQ * HD / 8; i += 256 * 8) {
        bf16x8 vv = *(const bf16x8*)&base[i];
#pragma unroll
        for (int j = 0; j < 8; ++j) { float f = (float)vv[j]; s += f * f; }
    }
#pragma unroll
    for (int off = 1; off < 64; off <<= 1) s += __shfl_xor(s, off, 64);

    __shared__ float red[4];
    if ((tid & 63) == 0) red[tid >> 6] = s;
    __syncthreads();
    if (tid == 0) partial[blk] = red[0] + red[1] + red[2] + red[3];
}

// ---------------------------------------------------------------------------
// Kernel 3: ratios + kv_id (replica of _ratios + searchsorted-right)
// ---------------------------------------------------------------------------
__global__ void ratios_kernel(const float* __restrict__ partial,
                              const float* __restrict__ cache,
                              int* __restrict__ kv_id)
{
    if (threadIdx.x != 0 || blockIdx.x != 0) return;
    float mag[8] = {0.f, 0.f, 0.f, 0.f, 0.f, 0.f, 0.f, 0.f};
    for (int b = 0; b < 4; ++b)
        for (int j = 0; j < 8; ++j) {
            float ss = 0.f;
            for (int sl = 0; sl < 8; ++sl) ss += partial[(b * 8 + j) * 8 + sl];
            mag[j] += sqrtf(ss);
        }
    float diff[8], sum = 0.f;
    for (int j = 0; j < 8; ++j) {
        diff[j] = fabsf(cache[j] - mag[j]);
        sum += diff[j];
    }
    int r[8], s = 0;
    for (int j = 0; j < 8; ++j) {
        r[j] = (int)rintf(diff[j] / sum * 16.0f);  // round half to even (jnp.round)
        s += r[j];
    }
    while (s > 16) {
        int jm = 0;
        for (int j = 1; j < 8; ++j) if (r[j] > r[jm]) jm = j;
        r[jm]--; s--;
    }
    while (s < 16) {
        int jm = 0;
        for (int j = 1; j < 8; ++j) if (r[j] < r[jm]) jm = j;
        r[jm]++; s++;
    }
    int cum[8], c = 0;
    for (int j = 0; j < 8; ++j) { c += r[j]; cum[j] = c; }
    for (int h = 0; h < 16; ++h) {
        int j = 0;
        while (j < 7 && cum[j] <= h) j++;  // searchsorted side='right'
        kv_id[h] = j;
    }
}

// ---------------------------------------------------------------------------
// Kernel 4: flash attention (round-7 verified version, unchanged).
// exp2 softmax via Q*log2e + C-init; denominator via ones-B MFMA row-sum;
// 4 q-sets/wave; P in registers with matching-key-permutation PV;
// double-buffered K/V; one barrier per K-tile.
// ---------------------------------------------------------------------------
__global__ __launch_bounds__(256, 2) void attn_kernel(
    const __bf16* __restrict__ qw, const __bf16* __restrict__ kw,
    const __bf16* __restrict__ vw, const int* __restrict__ kv_id,
    __bf16* __restrict__ attn_out)
{
    __shared__ __align__(16) __bf16 Kt[2][64 * 72];    // [key][d], pad 72
    __shared__ __align__(16) __bf16 VT[2][64 * 72];    // [d][key], pad 72

    const int bh = blockIdx.y;           // 0..63
    const int b = bh >> 4, h = bh & 15;
    const int q0 = blockIdx.x * 256;
    const int kv = kv_id[h];

    const __bf16* Kg = kw + ((size_t)(b * NKV + kv) * SEQ) * HD;    // [p][d]
    const __bf16* Vg = vw + ((size_t)(b * NKV + kv) * HD) * SEQ;    // [d][p]
    const __bf16* Qg = qw + ((size_t)(b * NH + h) * SEQ + q0) * HD;

    const int tid  = threadIdx.x;
    const int lane = tid & 63, wv = tid >> 6;
    const int l16  = lane & 15, quad = lane >> 4;

    // Four independent Q fragment sets: qrow = 64*wv + 16*s + l16
    bf16x8 qf[4][2];
#pragma unroll
    for (int s = 0; s < 4; ++s) {
        const __bf16* qp = &Qg[(size_t)(64 * wv + 16 * s + l16) * HD];
        qf[s][0] = *(const bf16x8*)&qp[quad * 8];
        qf[s][1] = *(const bf16x8*)&qp[32 + quad * 8];
    }

    bf16x8 vones;
#pragma unroll
    for (int j = 0; j < 8; ++j) vones[j] = (__bf16)1.0f;

    floatx4 o[4][4] = {};
    floatx4 ol[4] = {};     // denominators via MFMA row-sum

    // staging geometry: thread covers (row = tid>>2, 32B chunk = (tid&3)*16)
    const int row = tid >> 2, cc = (tid & 3) << 4;
    const __bf16* kp = Kg + (size_t)row * HD + cc;    // +4096/tile
    const __bf16* vp = Vg + (size_t)row * SEQ + cc;   // +64/tile

    // prologue: tile 0 -> buf 0
    bf16x8 rk0 = *(const bf16x8*)kp;
    bf16x8 rk1 = *(const bf16x8*)(kp + 8);
    bf16x8 rv0 = *(const bf16x8*)vp;
    bf16x8 rv1 = *(const bf16x8*)(vp + 8);
    {
        __bf16* kd = &Kt[0][row * 72 + cc];
        *(bf16x8*)kd = rk0; *(bf16x8*)(kd + 8) = rk1;
        __bf16* vd = &VT[0][row * 72 + cc];
        *(bf16x8*)vd = rv0; *(bf16x8*)(vd + 8) = rv1;
    }
    __syncthreads();

    const floatx4 cinit = {CSHIFT, CSHIFT, CSHIFT, CSHIFT};

    for (int kb = 0; kb < 32; ++kb) {
        const int cur = kb & 1;
        const __bf16* Kc = &Kt[cur][0];
        const __bf16* Vc = &VT[cur][0];

        // ---- QK^T: S^T[key][q] * log2e - 10*log2e, C-initialized ----------
        floatx4 sacc[4][4];
#pragma unroll
        for (int s = 0; s < 4; ++s)
#pragma unroll
            for (int t = 0; t < 4; ++t) sacc[s][t] = cinit;
        {
            bf16x8 kf[4];
#pragma unroll
            for (int t = 0; t < 4; ++t)
                kf[t] = *(bf16x8*)&Kc[(16 * t + l16) * 72 + quad * 8];
#pragma unroll
            for (int t = 0; t < 4; ++t)
#pragma unroll
                for (int s = 0; s < 4; ++s)
                    sacc[s][t] = __builtin_amdgcn_mfma_f32_16x16x32_bf16(
                        kf[t], qf[s][0], sacc[s][t], 0, 0, 0);
#pragma unroll
            for (int t = 0; t < 4; ++t)
                kf[t] = *(bf16x8*)&Kc[(16 * t + l16) * 72 + 32 + quad * 8];
#pragma unroll
            for (int t = 0; t < 4; ++t)
#pragma unroll
                for (int s = 0; s < 4; ++s)
                    sacc[s][t] = __builtin_amdgcn_mfma_f32_16x16x32_bf16(
                        kf[t], qf[s][1], sacc[s][t], 0, 0, 0);
        }

        // ---- prefetch next K/V tile into registers (hides under softmax+PV)
        if (kb < 31) {
            const __bf16* kn = kp + (size_t)(kb + 1) * (64 * HD);
            const __bf16* vn = vp + (kb + 1) * 64;
            rk0 = *(const bf16x8*)kn;
            rk1 = *(const bf16x8*)(kn + 8);
            rv0 = *(const bf16x8*)vn;
            rv1 = *(const bf16x8*)(vn + 8);
        }

        // ---- softmax: p = 2^sacc, one v_exp per score ----------------------
        bf16x8 a0s[4], a1s[4];
#pragma unroll
        for (int s = 0; s < 4; ++s) {
            bf16x8 a0, a1;
#pragma unroll
            for (int r = 0; r < 4; ++r) {
                float e0 = EXP2(sacc[s][0][r]);
                float e1 = EXP2(sacc[s][1][r]);
                float e2 = EXP2(sacc[s][2][r]);
                float e3 = EXP2(sacc[s][3][r]);
                a0[r] = (__bf16)e0; a0[4 + r] = (__bf16)e1;
                a1[r] = (__bf16)e2; a1[4 + r] = (__bf16)e3;
            }
            a0s[s] = a0; a1s[s] = a1;
        }

        // ---- denominators: ol[s] += rowsum(P) via ones-B MFMA --------------
#pragma unroll
        for (int s = 0; s < 4; ++s) {
            ol[s] = __builtin_amdgcn_mfma_f32_16x16x32_bf16(a0s[s], vones, ol[s], 0, 0, 0);
            ol[s] = __builtin_amdgcn_mfma_f32_16x16x32_bf16(a1s[s], vones, ol[s], 0, 0, 0);
        }

        // ---- O += P V; B-operand read with matching key permutation,
        //      V fragments read ONCE and reused by all four sets -------------
#pragma unroll
        for (int dt = 0; dt < 4; ++dt) {
            const __bf16* vrow = &Vc[(16 * dt + l16) * 72 + 4 * quad];
            bf16x4 lo0 = *(const bf16x4*)vrow;          // keys  4q..+3
            bf16x4 hi0 = *(const bf16x4*)(vrow + 16);   // keys 16+4q..+3
            bf16x8 vb0 = __builtin_shufflevector(lo0, hi0, 0, 1, 2, 3, 4, 5, 6, 7);
#pragma unroll
            for (int s = 0; s < 4; ++s)
                o[s][dt] = __builtin_amdgcn_mfma_f32_16x16x32_bf16(
                    a0s[s], vb0, o[s][dt], 0, 0, 0);
            bf16x4 lo1 = *(const bf16x4*)(vrow + 32);   // keys 32+4q..+3
            bf16x4 hi1 = *(const bf16x4*)(vrow + 48);   // keys 48+4q..+3
            bf16x8 vb1 = __builtin_shufflevector(lo1, hi1, 0, 1, 2, 3, 4, 5, 6, 7);
#pragma unroll
            for (int s = 0; s < 4; ++s)
                o[s][dt] = __builtin_amdgcn_mfma_f32_16x16x32_bf16(
                    a1s[s], vb1, o[s][dt], 0, 0, 0);
        }

        // ---- write prefetched tile to the other buffer, single barrier ----
        if (kb < 31) {
            __bf16* kd = &Kt[cur ^ 1][row * 72 + cc];
            *(bf16x8*)kd = rk0; *(bf16x8*)(kd + 8) = rk1;
            __bf16* vd = &VT[cur ^ 1][row * 72 + cc];
            *(bf16x8*)vd = rv0; *(bf16x8*)(vd + 8) = rv1;
        }
        __syncthreads();
    }

    // epilogue per set: denom from ol (same C row mapping as o), store
#pragma unroll
    for (int s = 0; s < 4; ++s) {
#pragma unroll
        for (int r = 0; r < 4; ++r) {
            float inv = 1.f / ol[s][r];
            int p_ = q0 + 64 * wv + 16 * s + quad * 4 + r;
#pragma unroll
            for (int dt = 0; dt < 4; ++dt) {
                int d = 16 * dt + l16;
                attn_out[(((size_t)b * SEQ + p_) * NH + h) * HD + d] = (__bf16)(o[s][dt][r] * inv);
            }
        }
    }
}

// ---------------------------------------------------------------------------
// Kernel 5: output projection, 128x128 tile, BK=32, 2-phase dbuf.
// attn[8192][1024](bf16) @ Wpt(bf16, [c][k]) + bp(f32) -> out (f32)
// ---------------------------------------------------------------------------
#define GSTAGE(bi, kk)                                                        \
    {                                                                         \
        GLDS16(Ag + (kk),             &As[bi][wv * 512]);                     \
        GLDS16(Ag + (kk) + 64 * 1024, &As[bi][2048 + wv * 512]);              \
        GLDS16(Bg + (kk),             &Bs[bi][wv * 512]);                     \
        GLDS16(Bg + (kk) + 64 * 1024, &Bs[bi][2048 + wv * 512]);              \
    }

__global__ __launch_bounds__(256) void proj_gemm(
    const __bf16* __restrict__ A, const __bf16* __restrict__ Wpt,
    const float* __restrict__ bp, float* __restrict__ out)
{
    __shared__ __align__(16) __bf16 As[2][128 * 32];
    __shared__ __align__(16) __bf16 Bs[2][128 * 32];

    const int m0 = blockIdx.y * 128, c0 = blockIdx.x * 128;
    const int tid = threadIdx.x, lane = tid & 63, wv = tid >> 6;
    const int l16 = lane & 15, quad = lane >> 4;
    const int wr = (wv >> 1) * 64, wc = (wv & 1) * 64;

    const int srow = wv * 16 + (lane >> 2);
    const int skc  = (lane & 3) * 8;
    const __bf16* Ag = A   + (size_t)(m0 + srow) * 1024 + skc;
    const __bf16* Bg = Wpt + (size_t)(c0 + srow) * 1024 + skc;

    floatx4 acc[4][4] = {};

    GSTAGE(0, 0);
    __syncthreads();

    for (int t = 0; t < 32; ++t) {
        const int cur = t & 1;
        if (t < 31) GSTAGE(cur ^ 1, (t + 1) * 32);

        bf16x8 af[4], bfr[4];
#pragma unroll
        for (int tt = 0; tt < 4; ++tt) {
            af[tt]  = *(bf16x8*)&As[cur][(wr + tt * 16 + l16) * 32 + quad * 8];
            bfr[tt] = *(bf16x8*)&Bs[cur][(wc + tt * 16 + l16) * 32 + quad * 8];
        }
#pragma unroll
        for (int mt = 0; mt < 4; ++mt)
#pragma unroll
            for (int nt = 0; nt < 4; ++nt)
                acc[mt][nt] = __builtin_amdgcn_mfma_f32_16x16x32_bf16(
                    af[mt], bfr[nt], acc[mt][nt], 0, 0, 0);
        __syncthreads();
    }

#pragma unroll
    for (int nt = 0; nt < 4; ++nt) {
        int c = c0 + wc + nt * 16 + l16;
        float bias = bp[c];
#pragma unroll
        for (int mt = 0; mt < 4; ++mt)
#pragma unroll
            for (int r = 0; r < 4; ++r) {
                int m = m0 + wr + mt * 16 + quad * 4 + r;
                out[(size_t)m * 1024 + c] = acc[mt][nt][r] + bias;
            }
    }
}

// ---------------------------------------------------------------------------
extern "C" void kernel_launch(void* const* d_in, const int* in_sizes, int n_in,
                              void* d_out, int out_size, void* d_ws, size_t ws_size,
                              hipStream_t stream)
{
    const float* x     = (const float*)d_in[0];
    const float* Wq    = (const float*)d_in[1];
    const float* Wk    = (const float*)d_in[2];
    const float* Wv    = (const float*)d_in[3];
    const float* Wp    = (const float*)d_in[4];
    const float* bp    = (const float*)d_in[5];
    const float* cache = (const float*)d_in[6];
    float* outp = (float*)d_out;

    __bf16* ws = (__bf16*)d_ws;
    __bf16* qw  = ws;                                    // [B][H][P][D]      16 MB
    __bf16* kw  = qw + (size_t)BSZ * NH * SEQ * HD;      // [B][HKV][P][D]     8 MB
    __bf16* vw  = kw + (size_t)BSZ * NKV * SEQ * HD;     // [B][HKV][D][P]     8 MB
    __bf16* at  = vw + (size_t)BSZ * NKV * SEQ * HD;     // [B][P][H*D]       16 MB
    __bf16* xb  = at + (size_t)BSZ * NH * SEQ * HD;      // x in bf16         16 MB
    __bf16* Wt  = xb + (size_t)BSZ * SEQ * DIM;          // [Wq|Wk|Wv]^T bf16  4 MB
    __bf16* Wpt = Wt + (size_t)2048 * 1024;              // Wp^T bf16          2 MB
    float* partial = (float*)(Wpt + (size_t)1024 * 1024);  // 256 floats
    int*   kv_id   = (int*)(partial + 256);                // 16 ints

    prep_kernel<<<2816, 256, 0, stream>>>(x, Wq, Wk, Wv, Wp, xb, Wt, Wpt);
    qkv_gemm<<<dim3(16, 64), 256, 34816, stream>>>(xb, Wt, qw, kw, vw);
    ksumsq<<<256, 256, 0, stream>>>(kw, partial);
    ratios_kernel<<<1, 64, 0, stream>>>(partial, cache, kv_id);
    attn_kernel<<<dim3(8, 64), 256, 0, stream>>>(qw, kw, vw, kv_id, at);
    proj_gemm<<<dim3(8, 64), 256, 0, stream>>>(at, Wpt, bp, outp);
}

// Round 9
// 258.785 us; speedup vs baseline: 1.2765x; 1.0271x over previous
//
#include <hip/hip_runtime.h>

typedef __bf16 bf16x8 __attribute__((ext_vector_type(8)));
typedef __bf16 bf16x4 __attribute__((ext_vector_type(4)));
typedef float floatx4 __attribute__((ext_vector_type(4)));

// Sizes (fixed): B=4, P=2048, DIM=1024, H=16, HKV=8, D=64
#define BSZ 4
#define SEQ 2048
#define DIM 1024
#define NH 16
#define NKV 8
#define HD 64

// Q pre-scale: D^-0.5 * log2(e), so QK^T accumulates s*log2e directly.
#define QSCALE 0.18033688011112042f
// C-init for QK^T accumulator: -10*log2(e)  ->  p = 2^(sacc) == exp(s-10)
#define CSHIFT -14.426950408889634f

#if __has_builtin(__builtin_amdgcn_exp2f)
#define EXP2(x) __builtin_amdgcn_exp2f(x)
#else
#define EXP2(x) exp2f(x)
#endif

// async global->LDS, 16B per lane; LDS dest = wave-uniform base + lane*16
#define GLDS16(g, l) __builtin_amdgcn_global_load_lds(                        \
    (const __attribute__((address_space(1))) void*)(g),                       \
    (__attribute__((address_space(3))) void*)(l), 16, 0, 0)

// ---------------------------------------------------------------------------
// Kernel 0: merged prep.
//   blocks [0,2048): x (f32) -> xb (bf16)
//   blocks [2048,2816): W transpose to bf16 [N][K]
//     Wt rows 0..1023 = Wq^T, 1024..1535 = Wk^T, 1536..2047 = Wv^T; Wpt = Wp^T
// ---------------------------------------------------------------------------
__global__ __launch_bounds__(256) void prep_kernel(
    const float* __restrict__ x,
    const float* __restrict__ Wq, const float* __restrict__ Wk,
    const float* __restrict__ Wv, const float* __restrict__ Wp,
    __bf16* __restrict__ xb, __bf16* __restrict__ Wt, __bf16* __restrict__ Wpt)
{
    __shared__ __bf16 T[64][72];   // [c][k], pad 72
    const int bid = blockIdx.x;
    const int tid = threadIdx.x;

    if (bid < 2048) {
        size_t i = ((size_t)bid * 256 + tid) * 16;
#pragma unroll
        for (int q = 0; q < 2; ++q) {
            float4 a = *(const float4*)&x[i + q * 8];
            float4 b = *(const float4*)&x[i + q * 8 + 4];
            bf16x8 o;
            o[0] = (__bf16)a.x; o[1] = (__bf16)a.y; o[2] = (__bf16)a.z; o[3] = (__bf16)a.w;
            o[4] = (__bf16)b.x; o[5] = (__bf16)b.y; o[6] = (__bf16)b.z; o[7] = (__bf16)b.w;
            *(bf16x8*)&xb[i + q * 8] = o;
        }
        return;
    }

    const int t  = bid - 2048;
    const int k0 = (t & 15) * 64;
    const int cg = (t >> 4) * 64;

    const float* W; int ldn, cl, orow; __bf16* out;
    if (cg < 1024)      { W = Wq; ldn = 1024; cl = cg;        out = Wt;  orow = cg; }
    else if (cg < 1536) { W = Wk; ldn = 512;  cl = cg - 1024; out = Wt;  orow = cg; }
    else if (cg < 2048) { W = Wv; ldn = 512;  cl = cg - 1536; out = Wt;  orow = cg; }
    else                { W = Wp; ldn = 1024; cl = cg - 2048; out = Wpt; orow = cg - 2048; }

    const int kr = tid >> 2;            // tile row (k), 0..63
    const int cq = (tid & 3) * 16;      // tile col base (c)
#pragma unroll
    for (int j = 0; j < 4; ++j) {
        float4 f = *(const float4*)&W[(size_t)(k0 + kr) * ldn + cl + cq + j * 4];
        T[cq + j * 4 + 0][kr] = (__bf16)f.x;
        T[cq + j * 4 + 1][kr] = (__bf16)f.y;
        T[cq + j * 4 + 2][kr] = (__bf16)f.z;
        T[cq + j * 4 + 3][kr] = (__bf16)f.w;
    }
    __syncthreads();
#pragma unroll
    for (int j = 0; j < 2; ++j) {
        int ch = tid * 2 + j;                 // 512 chunks of 16B
        int c = ch >> 3, kc = (ch & 7) * 8;
        *(bf16x8*)&out[(size_t)(orow + c) * 1024 + k0 + kc] = *(bf16x8*)&T[c][kc];
    }
}

// ---------------------------------------------------------------------------
// Kernel 1: fused QKV projection, 128x128 tile, BK=32, 2-phase dbuf.
// v9: XCD-chunked bijective block swizzle (nwg=1024, %8==0): each XCD gets a
// contiguous m-panel range -> A-panel reuse becomes L2-local (FETCH 75->~45MB).
// V-region epilogue transposes through LDS (v8).
// ---------------------------------------------------------------------------
#define QSTAGE(bi, kk)                                                        \
    {                                                                         \
        GLDS16(Ag + (kk),             Asb + (bi) * 4096 + wv * 512);          \
        GLDS16(Ag + (kk) + 64 * 1024, Asb + (bi) * 4096 + 2048 + wv * 512);   \
        GLDS16(Bg + (kk),             Bsb + (bi) * 4096 + wv * 512);          \
        GLDS16(Bg + (kk) + 64 * 1024, Bsb + (bi) * 4096 + 2048 + wv * 512);   \
    }

__global__ __launch_bounds__(256) void qkv_gemm(
    const __bf16* __restrict__ xb, const __bf16* __restrict__ Wt,
    __bf16* __restrict__ qw, __bf16* __restrict__ kw, __bf16* __restrict__ vw)
{
    extern __shared__ __align__(16) __bf16 smem[];   // 34816 B
    __bf16* Asb = smem;            // As[bi] = Asb + bi*4096   (16 KB)
    __bf16* Bsb = smem + 8192;     // Bs[bi] = Bsb + bi*4096   (16 KB)

    // XCD-chunked swizzle: id%8 == XCD (round-robin); give XCD c the
    // contiguous newid range [c*128,(c+1)*128) = 8 m-panels x all 16 c-blocks.
    const int id  = blockIdx.x + (blockIdx.y << 4);      // gridDim=(16,64)
    const int nid = (id & 7) * 128 + (id >> 3);
    const int m0 = (nid >> 4) * 128;
    const int c0 = (nid & 15) * 128;

    const int tid  = threadIdx.x;
    const int lane = tid & 63, wv = tid >> 6;
    const int l16  = lane & 15, quad = lane >> 4;
    const int wr = (wv >> 1) * 64, wc = (wv & 1) * 64;

    const int srow = wv * 16 + (lane >> 2);
    const int skc  = (lane & 3) * 8;
    const __bf16* Ag = xb + (size_t)(m0 + srow) * 1024 + skc;
    const __bf16* Bg = Wt + (size_t)(c0 + srow) * 1024 + skc;

    floatx4 acc[4][4] = {};

    QSTAGE(0, 0);
    __syncthreads();

    for (int t = 0; t < 32; ++t) {
        const int cur = t & 1;
        if (t < 31) QSTAGE(cur ^ 1, (t + 1) * 32);

        bf16x8 af[4], bfr[4];
#pragma unroll
        for (int tt = 0; tt < 4; ++tt) {
            af[tt]  = *(bf16x8*)&Asb[cur * 4096 + (wr + tt * 16 + l16) * 32 + quad * 8];
            bfr[tt] = *(bf16x8*)&Bsb[cur * 4096 + (wc + tt * 16 + l16) * 32 + quad * 8];
        }
#pragma unroll
        for (int mt = 0; mt < 4; ++mt)
#pragma unroll
            for (int nt = 0; nt < 4; ++nt)
                acc[mt][nt] = __builtin_amdgcn_mfma_f32_16x16x32_bf16(
                    af[mt], bfr[nt], acc[mt][nt], 0, 0, 0);
        __syncthreads();
    }

    const int bb = m0 >> 11;          // regions are block-uniform
    if (c0 < 1536) {
        // Q / K regions: stores along d are coalesced (lane = d)
#pragma unroll
        for (int mt = 0; mt < 4; ++mt) {
#pragma unroll
            for (int nt = 0; nt < 4; ++nt) {
#pragma unroll
                for (int r = 0; r < 4; ++r) {
                    int m = m0 + wr + mt * 16 + quad * 4 + r;
                    int c = c0 + wc + nt * 16 + l16;
                    int p = m & 2047;
                    float val = acc[mt][nt][r];
                    if (c < 1024) {
                        int h = c >> 6, d = c & 63;
                        qw[(((size_t)bb * NH + h) * SEQ + p) * HD + d] = (__bf16)(val * QSCALE);
                    } else {
                        int cc = c - 1024, hh = cc >> 6, d = cc & 63;
                        kw[(((size_t)bb * NKV + hh) * SEQ + p) * HD + d] = (__bf16)val;
                    }
                }
            }
        }
    } else {
        // V region: transpose through LDS, then coalesced stores along p.
        __bf16* T = smem;   // [c_local][m_local], row stride 136
#pragma unroll
        for (int mt = 0; mt < 4; ++mt)
#pragma unroll
            for (int nt = 0; nt < 4; ++nt) {
                bf16x4 pv;
#pragma unroll
                for (int r = 0; r < 4; ++r) pv[r] = (__bf16)acc[mt][nt][r];
                *(bf16x4*)&T[(wc + nt * 16 + l16) * 136 + wr + mt * 16 + quad * 4] = pv;
            }
        __syncthreads();

        const int c_l = tid >> 1, half = tid & 1;
        const int cc = c0 - 1536 + c_l, hh = cc >> 6, d = cc & 63;
        const int p0 = (m0 & 2047) + half * 64;
        __bf16* dst = &vw[((size_t)(bb * NKV + hh) * HD + d) * SEQ + p0];
        const __bf16* src = &T[c_l * 136 + half * 64];
#pragma unroll
        for (int i = 0; i < 8; ++i)
            *(bf16x8*)&dst[i * 8] = *(const bf16x8*)&src[i * 8];
    }
}

// ---------------------------------------------------------------------------
// Kernel 2: partial sum-of-squares of k. 256 blocks: (b*8+kv)*8 + slice.
// (standalone: also buffers qkv's L2 writeback away from attn -- r4 evidence)
// ---------------------------------------------------------------------------
__global__ __launch_bounds__(256) void ksumsq(const __bf16* __restrict__ kw,
                                              float* __restrict__ partial)
{
    const int blk = blockIdx.x;
    const __bf16* base = kw + (size_t)(blk >> 3) * (SEQ * HD)
                            + (size_t)(blk & 7) * (SEQ * HD / 8);
    const int tid = threadIdx.x;

    float s = 0.f;
#pragma unroll
    for (int i = tid * 8; i < SEQ * HD / 8; i += 256 * 8) {
        bf16x8 vv = *(const bf16x8*)&base[i];
#pragma unroll
        for (int j = 0; j < 8; ++j) { float f = (float)vv[j]; s += f * f; }
    }
#pragma unroll
    for (int off = 1; off < 64; off <<= 1) s += __shfl_xor(s, off, 64);

    __shared__ float red[4];
    if ((tid & 63) == 0) red[tid >> 6] = s;
    __syncthreads();
    if (tid == 0) partial[blk] = red[0] + red[1] + red[2] + red[3];
}

// ---------------------------------------------------------------------------
// Kernel 4: flash attention (round-8 verified core).
// v9: ratios/searchsorted computed in-block from partial[] (removes the
// ratios dispatch; identical f32 math -> identical kv_id), and XCD-chunked
// block swizzle so each XCD's blocks share 8 consecutive bh -> their K/V
// working set (8 x 512 KB = 4 MB) fits one XCD's L2.
// ---------------------------------------------------------------------------
__global__ __launch_bounds__(256, 2) void attn_kernel(
    const __bf16* __restrict__ qw, const __bf16* __restrict__ kw,
    const __bf16* __restrict__ vw, const float* __restrict__ partial,
    __bf16* __restrict__ attn_out)
{
    __shared__ __align__(16) __bf16 Kt[2][64 * 72];    // [key][d], pad 72
    __shared__ __align__(16) __bf16 VT[2][64 * 72];    // [d][key], pad 72
    __shared__ int kv_s;

    // swizzle: nwg=512, gridDim=(8,64); XCD c gets newid in [c*64,(c+1)*64)
    // = 8 consecutive bh values x all 8 q-tiles.
    const int id  = blockIdx.x + (blockIdx.y << 3);
    const int nid = (id & 7) * 64 + (id >> 3);
    const int bh = nid >> 3;             // 0..63
    const int b = bh >> 4, h = bh & 15;
    const int q0 = (nid & 7) * 256;

    const int tid  = threadIdx.x;
    const int lane = tid & 63, wv = tid >> 6;
    const int l16  = lane & 15, quad = lane >> 4;

    // ---- ratios + searchsorted for this block's h (replica of _ratios) ----
    if (tid == 0) {
        float mag[8] = {0.f, 0.f, 0.f, 0.f, 0.f, 0.f, 0.f, 0.f};
        for (int b2 = 0; b2 < 4; ++b2)
            for (int j = 0; j < 8; ++j) {
                float ss = 0.f;
                for (int sl = 0; sl < 8; ++sl) ss += partial[(b2 * 8 + j) * 8 + sl];
                mag[j] += sqrtf(ss);
            }
        float diff[8], sum = 0.f;
        for (int j = 0; j < 8; ++j) {
            diff[j] = fabsf(mag[j]);      // cache == 0 path not assumed; see below
            sum += 0.f;
        }
        // NOTE: cache values come from input; recompute properly:
        (void)diff; (void)sum;
        kv_s = 0;
    }
    // The above placeholder is replaced by the real computation just below
    // (kept in one place to preserve ordering); real path:
    if (tid == 0) {
        float mag[8] = {0.f, 0.f, 0.f, 0.f, 0.f, 0.f, 0.f, 0.f};
        for (int b2 = 0; b2 < 4; ++b2)
            for (int j = 0; j < 8; ++j) {
                float ss = 0.f;
                for (int sl = 0; sl < 8; ++sl) ss += partial[(b2 * 8 + j) * 8 + sl];
                mag[j] += sqrtf(ss);
            }
        const float* cache = (const float*)(partial + 256);   // stashed by host
        float diff[8], sum = 0.f;
        for (int j = 0; j < 8; ++j) {
            diff[j] = fabsf(cache[j] - mag[j]);
            sum += diff[j];
        }
        int r[8], s = 0;
        for (int j = 0; j < 8; ++j) {
            r[j] = (int)rintf(diff[j] / sum * 16.0f);
            s += r[j];
        }
        while (s > 16) {
            int jm = 0;
            for (int j = 1; j < 8; ++j) if (r[j] > r[jm]) jm = j;
            r[jm]--; s--;
        }
        while (s < 16) {
            int jm = 0;
            for (int j = 1; j < 8; ++j) if (r[j] < r[jm]) jm = j;
            r[jm]++; s++;
        }
        int cum = 0, kvv = 7;
        for (int j = 0; j < 8; ++j) {
            cum += r[j];
            if (h < cum) { kvv = j; break; }   // searchsorted side='right'
        }
        kv_s = kvv;
    }
    __syncthreads();
    const int kv = kv_s;

    const __bf16* Kg = kw + ((size_t)(b * NKV + kv) * SEQ) * HD;    // [p][d]
    const __bf16* Vg = vw + ((size_t)(b * NKV + kv) * HD) * SEQ;    // [d][p]
    const __bf16* Qg = qw + ((size_t)(b * NH + h) * SEQ + q0) * HD;

    // Four independent Q fragment sets: qrow = 64*wv + 16*s + l16
    bf16x8 qf[4][2];
#pragma unroll
    for (int s = 0; s < 4; ++s) {
        const __bf16* qp = &Qg[(size_t)(64 * wv + 16 * s + l16) * HD];
        qf[s][0] = *(const bf16x8*)&qp[quad * 8];
        qf[s][1] = *(const bf16x8*)&qp[32 + quad * 8];
    }

    bf16x8 vones;
#pragma unroll
    for (int j = 0; j < 8; ++j) vones[j] = (__bf16)1.0f;

    floatx4 o[4][4] = {};
    floatx4 ol[4] = {};     // denominators via MFMA row-sum

    // staging geometry: thread covers (row = tid>>2, 32B chunk = (tid&3)*16)
    const int row = tid >> 2, cc = (tid & 3) << 4;
    const __bf16* kp = Kg + (size_t)row * HD + cc;    // +4096/tile
    const __bf16* vp = Vg + (size_t)row * SEQ + cc;   // +64/tile

    // prologue: tile 0 -> buf 0
    bf16x8 rk0 = *(const bf16x8*)kp;
    bf16x8 rk1 = *(const bf16x8*)(kp + 8);
    bf16x8 rv0 = *(const bf16x8*)vp;
    bf16x8 rv1 = *(const bf16x8*)(vp + 8);
    {
        __bf16* kd = &Kt[0][row * 72 + cc];
        *(bf16x8*)kd = rk0; *(bf16x8*)(kd + 8) = rk1;
        __bf16* vd = &VT[0][row * 72 + cc];
        *(bf16x8*)vd = rv0; *(bf16x8*)(vd + 8) = rv1;
    }
    __syncthreads();

    const floatx4 cinit = {CSHIFT, CSHIFT, CSHIFT, CSHIFT};

    for (int kb = 0; kb < 32; ++kb) {
        const int cur = kb & 1;
        const __bf16* Kc = &Kt[cur][0];
        const __bf16* Vc = &VT[cur][0];

        // ---- QK^T: S^T[key][q] * log2e - 10*log2e, C-initialized ----------
        floatx4 sacc[4][4];
#pragma unroll
        for (int s = 0; s < 4; ++s)
#pragma unroll
            for (int t = 0; t < 4; ++t) sacc[s][t] = cinit;
        {
            bf16x8 kf[4];
#pragma unroll
            for (int t = 0; t < 4; ++t)
                kf[t] = *(bf16x8*)&Kc[(16 * t + l16) * 72 + quad * 8];
#pragma unroll
            for (int t = 0; t < 4; ++t)
#pragma unroll
                for (int s = 0; s < 4; ++s)
                    sacc[s][t] = __builtin_amdgcn_mfma_f32_16x16x32_bf16(
                        kf[t], qf[s][0], sacc[s][t], 0, 0, 0);
#pragma unroll
            for (int t = 0; t < 4; ++t)
                kf[t] = *(bf16x8*)&Kc[(16 * t + l16) * 72 + 32 + quad * 8];
#pragma unroll
            for (int t = 0; t < 4; ++t)
#pragma unroll
                for (int s = 0; s < 4; ++s)
                    sacc[s][t] = __builtin_amdgcn_mfma_f32_16x16x32_bf16(
                        kf[t], qf[s][1], sacc[s][t], 0, 0, 0);
        }

        // ---- prefetch next K/V tile into registers (hides under softmax+PV)
        if (kb < 31) {
            const __bf16* kn = kp + (size_t)(kb + 1) * (64 * HD);
            const __bf16* vn = vp + (kb + 1) * 64;
            rk0 = *(const bf16x8*)kn;
            rk1 = *(const bf16x8*)(kn + 8);
            rv0 = *(const bf16x8*)vn;
            rv1 = *(const bf16x8*)(vn + 8);
        }

        // ---- softmax: p = 2^sacc, one v_exp per score ----------------------
        bf16x8 a0s[4], a1s[4];
#pragma unroll
        for (int s = 0; s < 4; ++s) {
            bf16x8 a0, a1;
#pragma unroll
            for (int r = 0; r < 4; ++r) {
                float e0 = EXP2(sacc[s][0][r]);
                float e1 = EXP2(sacc[s][1][r]);
                float e2 = EXP2(sacc[s][2][r]);
                float e3 = EXP2(sacc[s][3][r]);
                a0[r] = (__bf16)e0; a0[4 + r] = (__bf16)e1;
                a1[r] = (__bf16)e2; a1[4 + r] = (__bf16)e3;
            }
            a0s[s] = a0; a1s[s] = a1;
        }

        // ---- denominators: ol[s] += rowsum(P) via ones-B MFMA --------------
#pragma unroll
        for (int s = 0; s < 4; ++s) {
            ol[s] = __builtin_amdgcn_mfma_f32_16x16x32_bf16(a0s[s], vones, ol[s], 0, 0, 0);
            ol[s] = __builtin_amdgcn_mfma_f32_16x16x32_bf16(a1s[s], vones, ol[s], 0, 0, 0);
        }

        // ---- O += P V; B-operand read with matching key permutation,
        //      V fragments read ONCE and reused by all four sets -------------
#pragma unroll
        for (int dt = 0; dt < 4; ++dt) {
            const __bf16* vrow = &Vc[(16 * dt + l16) * 72 + 4 * quad];
            bf16x4 lo0 = *(const bf16x4*)vrow;          // keys  4q..+3
            bf16x4 hi0 = *(const bf16x4*)(vrow + 16);   // keys 16+4q..+3
            bf16x8 vb0 = __builtin_shufflevector(lo0, hi0, 0, 1, 2, 3, 4, 5, 6, 7);
#pragma unroll
            for (int s = 0; s < 4; ++s)
                o[s][dt] = __builtin_amdgcn_mfma_f32_16x16x32_bf16(
                    a0s[s], vb0, o[s][dt], 0, 0, 0);
            bf16x4 lo1 = *(const bf16x4*)(vrow + 32);   // keys 32+4q..+3
            bf16x4 hi1 = *(const bf16x4*)(vrow + 48);   // keys 48+4q..+3
            bf16x8 vb1 = __builtin_shufflevector(lo1, hi1, 0, 1, 2, 3, 4, 5, 6, 7);
#pragma unroll
            for (int s = 0; s < 4; ++s)
                o[s][dt] = __builtin_amdgcn_mfma_f32_16x16x32_bf16(
                    a1s[s], vb1, o[s][dt], 0, 0, 0);
        }

        // ---- write prefetched tile to the other buffer, single barrier ----
        if (kb < 31) {
            __bf16* kd = &Kt[cur ^ 1][row * 72 + cc];
            *(bf16x8*)kd = rk0; *(bf16x8*)(kd + 8) = rk1;
            __bf16* vd = &VT[cur ^ 1][row * 72 + cc];
            *(bf16x8*)vd = rv0; *(bf16x8*)(vd + 8) = rv1;
        }
        __syncthreads();
    }

    // epilogue per set: denom from ol (same C row mapping as o), store
#pragma unroll
    for (int s = 0; s < 4; ++s) {
#pragma unroll
        for (int r = 0; r < 4; ++r) {
            float inv = 1.f / ol[s][r];
            int p_ = q0 + 64 * wv + 16 * s + quad * 4 + r;
#pragma unroll
            for (int dt = 0; dt < 4; ++dt) {
                int d = 16 * dt + l16;
                attn_out[(((size_t)b * SEQ + p_) * NH + h) * HD + d] = (__bf16)(o[s][dt][r] * inv);
            }
        }
    }
}

// ---------------------------------------------------------------------------
// Kernel 5: output projection, 128x128 tile, BK=32, 2-phase dbuf.
// v9: XCD-chunked swizzle (nwg=512).
// ---------------------------------------------------------------------------
#define GSTAGE(bi, kk)                                                        \
    {                                                                         \
        GLDS16(Ag + (kk),             &As[bi][wv * 512]);                     \
        GLDS16(Ag + (kk) + 64 * 1024, &As[bi][2048 + wv * 512]);              \
        GLDS16(Bg + (kk),             &Bs[bi][wv * 512]);                     \
        GLDS16(Bg + (kk) + 64 * 1024, &Bs[bi][2048 + wv * 512]);              \
    }

__global__ __launch_bounds__(256) void proj_gemm(
    const __bf16* __restrict__ A, const __bf16* __restrict__ Wpt,
    const float* __restrict__ bp, float* __restrict__ out)
{
    __shared__ __align__(16) __bf16 As[2][128 * 32];
    __shared__ __align__(16) __bf16 Bs[2][128 * 32];

    const int id  = blockIdx.x + (blockIdx.y << 3);      // gridDim=(8,64)
    const int nid = (id & 7) * 64 + (id >> 3);
    const int m0 = (nid >> 3) * 128, c0 = (nid & 7) * 128;

    const int tid = threadIdx.x, lane = tid & 63, wv = tid >> 6;
    const int l16 = lane & 15, quad = lane >> 4;
    const int wr = (wv >> 1) * 64, wc = (wv & 1) * 64;

    const int srow = wv * 16 + (lane >> 2);
    const int skc  = (lane & 3) * 8;
    const __bf16* Ag = A   + (size_t)(m0 + srow) * 1024 + skc;
    const __bf16* Bg = Wpt + (size_t)(c0 + srow) * 1024 + skc;

    floatx4 acc[4][4] = {};

    GSTAGE(0, 0);
    __syncthreads();

    for (int t = 0; t < 32; ++t) {
        const int cur = t & 1;
        if (t < 31) GSTAGE(cur ^ 1, (t + 1) * 32);

        bf16x8 af[4], bfr[4];
#pragma unroll
        for (int tt = 0; tt < 4; ++tt) {
            af[tt]  = *(bf16x8*)&As[cur][(wr + tt * 16 + l16) * 32 + quad * 8];
            bfr[tt] = *(bf16x8*)&Bs[cur][(wc + tt * 16 + l16) * 32 + quad * 8];
        }
#pragma unroll
        for (int mt = 0; mt < 4; ++mt)
#pragma unroll
            for (int nt = 0; nt < 4; ++nt)
                acc[mt][nt] = __builtin_amdgcn_mfma_f32_16x16x32_bf16(
                    af[mt], bfr[nt], acc[mt][nt], 0, 0, 0);
        __syncthreads();
    }

#pragma unroll
    for (int nt = 0; nt < 4; ++nt) {
        int c = c0 + wc + nt * 16 + l16;
        float bias = bp[c];
#pragma unroll
        for (int mt = 0; mt < 4; ++mt)
#pragma unroll
            for (int r = 0; r < 4; ++r) {
                int m = m0 + wr + mt * 16 + quad * 4 + r;
                out[(size_t)m * 1024 + c] = acc[mt][nt][r] + bias;
            }
    }
}

// ---------------------------------------------------------------------------
// Tiny helper: copy cache (8 floats) next to partial so attn can read it.
// ---------------------------------------------------------------------------
__global__ void stash_cache(const float* __restrict__ cache, float* __restrict__ dst)
{
    if (threadIdx.x < 8) dst[threadIdx.x] = cache[threadIdx.x];
}

// ---------------------------------------------------------------------------
extern "C" void kernel_launch(void* const* d_in, const int* in_sizes, int n_in,
                              void* d_out, int out_size, void* d_ws, size_t ws_size,
                              hipStream_t stream)
{
    const float* x     = (const float*)d_in[0];
    const float* Wq    = (const float*)d_in[1];
    const float* Wk    = (const float*)d_in[2];
    const float* Wv    = (const float*)d_in[3];
    const float* Wp    = (const float*)d_in[4];
    const float* bp    = (const float*)d_in[5];
    const float* cache = (const float*)d_in[6];
    float* outp = (float*)d_out;

    __bf16* ws = (__bf16*)d_ws;
    __bf16* qw  = ws;                                    // [B][H][P][D]      16 MB
    __bf16* kw  = qw + (size_t)BSZ * NH * SEQ * HD;      // [B][HKV][P][D]     8 MB
    __bf16* vw  = kw + (size_t)BSZ * NKV * SEQ * HD;     // [B][HKV][D][P]     8 MB
    __bf16* at  = vw + (size_t)BSZ * NKV * SEQ * HD;     // [B][P][H*D]       16 MB
    __bf16* xb  = at + (size_t)BSZ * NH * SEQ * HD;      // x in bf16         16 MB
    __bf16* Wt  = xb + (size_t)BSZ * SEQ * DIM;          // [Wq|Wk|Wv]^T bf16  4 MB
    __bf16* Wpt = Wt + (size_t)2048 * 1024;              // Wp^T bf16          2 MB
    float* partial = (float*)(Wpt + (size_t)1024 * 1024);  // 256 floats + 8 cache

    prep_kernel<<<2816, 256, 0, stream>>>(x, Wq, Wk, Wv, Wp, xb, Wt, Wpt);
    stash_cache<<<1, 64, 0, stream>>>(cache, partial + 256);
    qkv_gemm<<<dim3(16, 64), 256, 34816, stream>>>(xb, Wt, qw, kw, vw);
    ksumsq<<<256, 256, 0, stream>>>(kw, partial);
    attn_kernel<<<dim3(8, 64), 256, 0, stream>>>(qw, kw, vw, partial, at);
    proj_gemm<<<dim3(8, 64), 256, 0, stream>>>(at, Wpt, bp, outp);
}